// Round 1
// baseline (3414.022 us; speedup 1.0000x reference)
//
#include <hip/hip_runtime.h>
#include <math.h>

#define BB 2
#define TT 2048
#define DD 2048
#define HH 16
#define KK 128
#define VV 128
#define SPLIT 8
#define ROWS 16  // V-rows per scan block

// ---------------------------------------------------------------------------
// C[M,N] = A[M,Kd] * W[N,Kd]^T   (fp32, 128x128 block tile, 8x8 microtile)
// ---------------------------------------------------------------------------
__global__ __launch_bounds__(256) void gemm_nt(const float* __restrict__ A,
                                               const float* __restrict__ W,
                                               float* __restrict__ C,
                                               int M, int N, int Kd) {
  __shared__ float As[8][128];
  __shared__ float Bs[8][128];
  const int tid = threadIdx.x;
  const int bm = blockIdx.y * 128;
  const int bn = blockIdx.x * 128;
  const int lrow = tid >> 1;         // 0..127
  const int lcol = (tid & 1) * 4;    // 0 or 4
  const int rm = (tid >> 4) * 8;     // microtile row base
  const int rn = (tid & 15) * 8;     // microtile col base
  const float* Ap = A + (size_t)(bm + lrow) * Kd + lcol;
  const float* Wp = W + (size_t)(bn + lrow) * Kd + lcol;
  float acc[8][8];
#pragma unroll
  for (int i = 0; i < 8; i++)
#pragma unroll
    for (int j = 0; j < 8; j++) acc[i][j] = 0.f;

  for (int d0 = 0; d0 < Kd; d0 += 8) {
    const float4 av = *(const float4*)(Ap + d0);
    const float4 wv = *(const float4*)(Wp + d0);
    __syncthreads();  // previous iteration's reads done before overwrite
    As[lcol + 0][lrow] = av.x;
    As[lcol + 1][lrow] = av.y;
    As[lcol + 2][lrow] = av.z;
    As[lcol + 3][lrow] = av.w;
    Bs[lcol + 0][lrow] = wv.x;
    Bs[lcol + 1][lrow] = wv.y;
    Bs[lcol + 2][lrow] = wv.z;
    Bs[lcol + 3][lrow] = wv.w;
    __syncthreads();
#pragma unroll
    for (int kk = 0; kk < 8; kk++) {
      const float4 a0 = *(const float4*)&As[kk][rm];
      const float4 a1 = *(const float4*)&As[kk][rm + 4];
      const float4 b0 = *(const float4*)&Bs[kk][rn];
      const float4 b1 = *(const float4*)&Bs[kk][rn + 4];
      const float ar[8] = {a0.x, a0.y, a0.z, a0.w, a1.x, a1.y, a1.z, a1.w};
      const float br[8] = {b0.x, b0.y, b0.z, b0.w, b1.x, b1.y, b1.z, b1.w};
#pragma unroll
      for (int i = 0; i < 8; i++)
#pragma unroll
        for (int j = 0; j < 8; j++) acc[i][j] = fmaf(ar[i], br[j], acc[i][j]);
    }
  }
#pragma unroll
  for (int i = 0; i < 8; i++) {
    float* cp = C + (size_t)(bm + rm + i) * N + bn + rn;
    float4 c0 = {acc[i][0], acc[i][1], acc[i][2], acc[i][3]};
    float4 c1 = {acc[i][4], acc[i][5], acc[i][6], acc[i][7]};
    *(float4*)cp = c0;
    *(float4*)(cp + 4) = c1;
  }
}

// ---------------------------------------------------------------------------
// alpha = sigmoid(x@Wa^T + ba), beta = softplus(x@Wb^T + bb) * K^-0.5
// grid (B*T, 4): g=0,1 -> alpha heads 0-7 / 8-15 ; g=2,3 -> beta
// ---------------------------------------------------------------------------
__global__ __launch_bounds__(64) void ab_proj(const float* __restrict__ x,
                                              const float* __restrict__ Wa,
                                              const float* __restrict__ ba,
                                              const float* __restrict__ Wb,
                                              const float* __restrict__ bb,
                                              float* __restrict__ alpha,
                                              float* __restrict__ beta) {
  const int row = blockIdx.x;
  const int g = blockIdx.y;
  const int h0 = (g & 1) * 8;
  const bool isA = (g < 2);
  const float* W = isA ? Wa : Wb;
  const int lane = threadIdx.x;
  const float* xr = x + (size_t)row * DD;
  float acc[8];
#pragma unroll
  for (int j = 0; j < 8; j++) acc[j] = 0.f;
  for (int d = lane; d < DD; d += 64) {
    const float xv = xr[d];
#pragma unroll
    for (int j = 0; j < 8; j++)
      acc[j] = fmaf(xv, W[(size_t)(h0 + j) * DD + d], acc[j]);
  }
#pragma unroll
  for (int j = 0; j < 8; j++) {
#pragma unroll
    for (int off = 32; off > 0; off >>= 1) acc[j] += __shfl_xor(acc[j], off, 64);
  }
  if (lane == 0) {
    if (isA) {
#pragma unroll
      for (int j = 0; j < 8; j++) {
        const float z = acc[j] + ba[h0 + j];
        alpha[(size_t)row * HH + h0 + j] = 1.0f / (1.0f + expf(-z));
      }
    } else {
#pragma unroll
      for (int j = 0; j < 8; j++) {
        const float z = acc[j] + bb[h0 + j];
        const float sp = (z > 20.f) ? z : log1pf(expf(z));
        beta[(size_t)row * HH + h0 + j] = sp * 0.08838834764831845f;  // K^-0.5
      }
    }
  }
}

// ---------------------------------------------------------------------------
// In-place l2 normalization of q and k over last dim (K=128).
// grid = B*T*H blocks, 128 threads: wave0 -> q vector, wave1 -> k vector.
// ---------------------------------------------------------------------------
__global__ __launch_bounds__(128) void norm_qk(float* __restrict__ q,
                                               float* __restrict__ k) {
  const int vec = blockIdx.x;
  const int t = threadIdx.x;
  float* p = (t < 64 ? q : k) + (size_t)vec * 128;
  const int l = t & 63;
  const float x0 = p[l];
  const float x1 = p[l + 64];
  float ss = x0 * x0 + x1 * x1;
#pragma unroll
  for (int off = 32; off > 0; off >>= 1) ss += __shfl_xor(ss, off, 64);
  const float inv = 1.0f / fmaxf(sqrtf(ss), 1e-12f);
  p[l] = x0 * inv;
  p[l + 64] = x1 * inv;
}

// ---------------------------------------------------------------------------
// Gated delta rule scan. State rows are independent given (k,q,a,b,v[row]),
// so V=128 rows of each (b,h) state are split across SPLIT blocks.
// Block: 256 threads = 16 rows x 16 lanes; each thread holds 8 state floats.
// Double-buffered LDS staging of (k,q,v-slice,a,b); one barrier per step;
// global prefetch of step t+1 overlaps compute of step t.
// ---------------------------------------------------------------------------
__global__ __launch_bounds__(256) void scan_kernel(const float* __restrict__ q,
                                                   const float* __restrict__ k,
                                                   const float* __restrict__ v,
                                                   const float* __restrict__ alpha,
                                                   const float* __restrict__ beta,
                                                   float* __restrict__ o) {
  const int bid = blockIdx.x;
  const int s = bid % SPLIT;
  const int bh = bid / SPLIT;
  const int h = bh % HH;
  const int b = bh / HH;
  const int r0 = s * ROWS;
  const int t = threadIdx.x;
  const int vloc = t >> 4;   // 0..15 row within block
  const int kg = t & 15;     // 0..15 k-group (8 floats each)
  const int vrow = r0 + vloc;

  __shared__ float ks[2][128];
  __shared__ float qs[2][128];
  __shared__ float vs[2][ROWS];
  __shared__ float ab[2][2];

  float S[8];
#pragma unroll
  for (int i = 0; i < 8; i++) S[i] = 0.f;

  size_t base = (size_t)b * TT * (HH * KK) + (size_t)h * KK;  // +2048 per step
  size_t abase = (size_t)b * TT * HH + h;                     // +16 per step

  // stage step 0
  if (t < 128) ks[0][t] = k[base + t];
  else qs[0][t - 128] = q[base + (t - 128)];
  if (t < ROWS) vs[0][t] = v[base + r0 + t];
  if (t == 16) ab[0][0] = alpha[abase];
  if (t == 17) ab[0][1] = beta[abase];
  __syncthreads();

  int p = 0;
  for (int tt = 0; tt < TT; tt++) {
    // prefetch step tt+1 into registers (latency overlapped with compute)
    float pk = 0.f, pq = 0.f, pv = 0.f, pa = 0.f, pb = 0.f;
    const bool notlast = (tt + 1 < TT);
    if (notlast) {
      const size_t nb = base + (HH * KK);
      if (t < 128) pk = k[nb + t];
      else pq = q[nb + (t - 128)];
      if (t < ROWS) pv = v[nb + r0 + t];
      if (t == 16) pa = alpha[abase + HH];
      if (t == 17) pb = beta[abase + HH];
    }

    const float a = ab[p][0];
    const float bta = ab[p][1];
    const float vval = vs[p][vloc];
    const float4 ka = *(const float4*)&ks[p][kg * 8];
    const float4 kb = *(const float4*)&ks[p][kg * 8 + 4];
    const float4 qa = *(const float4*)&qs[p][kg * 8];
    const float4 qb = *(const float4*)&qs[p][kg * 8 + 4];
    const float kr[8] = {ka.x, ka.y, ka.z, ka.w, kb.x, kb.y, kb.z, kb.w};
    const float qr[8] = {qa.x, qa.y, qa.z, qa.w, qb.x, qb.y, qb.z, qb.w};

    // pred[v] = a * sum_k S[v,k]*k[k]
    float pp = 0.f;
#pragma unroll
    for (int i = 0; i < 8; i++) pp = fmaf(S[i], kr[i], pp);
    pp += __shfl_xor(pp, 1, 64);
    pp += __shfl_xor(pp, 2, 64);
    pp += __shfl_xor(pp, 4, 64);
    pp += __shfl_xor(pp, 8, 64);
    const float pred = a * pp;
    const float u = bta * (vval - pred);

    // S = a*S + u*k ; o_partial = S.q
    float op = 0.f;
#pragma unroll
    for (int i = 0; i < 8; i++) {
      S[i] = fmaf(a, S[i], u * kr[i]);
      op = fmaf(S[i], qr[i], op);
    }
    op += __shfl_xor(op, 1, 64);
    op += __shfl_xor(op, 2, 64);
    op += __shfl_xor(op, 4, 64);
    op += __shfl_xor(op, 8, 64);
    if (kg == 0) o[base + vrow] = op;  // o layout == q layout [B,T,H,128]

    if (notlast) {
      if (t < 128) ks[1 - p][t] = pk;
      else qs[1 - p][t - 128] = pq;
      if (t < ROWS) vs[1 - p][t] = pv;
      if (t == 16) ab[1 - p][0] = pa;
      if (t == 17) ab[1 - p][1] = pb;
    }
    __syncthreads();
    p ^= 1;
    base += (HH * KK);
    abase += HH;
  }
}

// ---------------------------------------------------------------------------
extern "C" void kernel_launch(void* const* d_in, const int* in_sizes, int n_in,
                              void* d_out, int out_size, void* d_ws,
                              size_t ws_size, hipStream_t stream) {
  const float* x = (const float*)d_in[0];
  const float* Wq = (const float*)d_in[1];
  const float* Wk = (const float*)d_in[2];
  const float* Wv = (const float*)d_in[3];
  const float* Wa = (const float*)d_in[4];
  const float* ba = (const float*)d_in[5];
  const float* Wb = (const float*)d_in[6];
  const float* bb = (const float*)d_in[7];
  float* out = (float*)d_out;
  float* ws = (float*)d_ws;

  const size_t PROJ = (size_t)BB * TT * HH * KK;  // 8,388,608 floats
  float* qw = ws;
  float* kw = ws + PROJ;
  float* vw = ws + 2 * PROJ;
  float* al = ws + 3 * PROJ;
  float* be = al + (size_t)BB * TT * HH;
  // total ws use: (3*PROJ + 2*B*T*H)*4 bytes ~= 96.5 MiB

  const int M = BB * TT;  // 4096
  const int N = HH * KK;  // 2048
  dim3 gg(N / 128, M / 128);
  gemm_nt<<<gg, 256, 0, stream>>>(x, Wq, qw, M, N, DD);
  gemm_nt<<<gg, 256, 0, stream>>>(x, Wk, kw, M, N, DD);
  gemm_nt<<<gg, 256, 0, stream>>>(x, Wv, vw, M, N, DD);
  ab_proj<<<dim3(M, 4), 64, 0, stream>>>(x, Wa, ba, Wb, bb, al, be);
  norm_qk<<<BB * TT * HH, 128, 0, stream>>>(qw, kw);
  scan_kernel<<<BB * HH * SPLIT, 256, 0, stream>>>(qw, kw, vw, al, be, out);
}

// Round 2
// 2588.203 us; speedup vs baseline: 1.3191x; 1.3191x over previous
//
#include <hip/hip_runtime.h>
#include <math.h>

#define BB 2
#define TT 2048
#define DD 2048
#define HH 16
#define KK 128
#define VV 128

// ---------------------------------------------------------------------------
// C[M,N] = A[M,Kd] * W[N,Kd]^T  (fp32, 128x128 tile, 8x8 microtile)
// blockIdx.z selects which of the 3 weight matrices / output slabs.
// Register prefetch of the next 8-k slab overlaps global latency with FMAs.
// ---------------------------------------------------------------------------
__global__ __launch_bounds__(256) void gemm_nt3(const float* __restrict__ A,
                                                const float* __restrict__ W0,
                                                const float* __restrict__ W1,
                                                const float* __restrict__ W2,
                                                float* __restrict__ Cbase,
                                                int M, int N, int Kd) {
  __shared__ float As[8][128];
  __shared__ float Bs[8][128];
  const int z = blockIdx.z;
  const float* W = (z == 0) ? W0 : (z == 1) ? W1 : W2;
  float* C = Cbase + (size_t)z * M * N;
  const int tid = threadIdx.x;
  const int bm = blockIdx.y * 128;
  const int bn = blockIdx.x * 128;
  const int lrow = tid >> 1;       // 0..127
  const int lcol = (tid & 1) * 4;  // 0 or 4
  const int rm = (tid >> 4) * 8;
  const int rn = (tid & 15) * 8;
  const float* Ap = A + (size_t)(bm + lrow) * Kd + lcol;
  const float* Wp = W + (size_t)(bn + lrow) * Kd + lcol;
  float acc[8][8];
#pragma unroll
  for (int i = 0; i < 8; i++)
#pragma unroll
    for (int j = 0; j < 8; j++) acc[i][j] = 0.f;

  float4 av = *(const float4*)Ap;
  float4 wv = *(const float4*)Wp;
  for (int d0 = 0; d0 < Kd; d0 += 8) {
    __syncthreads();
    As[lcol + 0][lrow] = av.x;
    As[lcol + 1][lrow] = av.y;
    As[lcol + 2][lrow] = av.z;
    As[lcol + 3][lrow] = av.w;
    Bs[lcol + 0][lrow] = wv.x;
    Bs[lcol + 1][lrow] = wv.y;
    Bs[lcol + 2][lrow] = wv.z;
    Bs[lcol + 3][lrow] = wv.w;
    __syncthreads();
    if (d0 + 8 < Kd) {  // prefetch next slab while computing this one
      av = *(const float4*)(Ap + d0 + 8);
      wv = *(const float4*)(Wp + d0 + 8);
    }
#pragma unroll
    for (int kk = 0; kk < 8; kk++) {
      const float4 a0 = *(const float4*)&As[kk][rm];
      const float4 a1 = *(const float4*)&As[kk][rm + 4];
      const float4 b0 = *(const float4*)&Bs[kk][rn];
      const float4 b1 = *(const float4*)&Bs[kk][rn + 4];
      const float ar[8] = {a0.x, a0.y, a0.z, a0.w, a1.x, a1.y, a1.z, a1.w};
      const float br[8] = {b0.x, b0.y, b0.z, b0.w, b1.x, b1.y, b1.z, b1.w};
#pragma unroll
      for (int i = 0; i < 8; i++)
#pragma unroll
        for (int j = 0; j < 8; j++) acc[i][j] = fmaf(ar[i], br[j], acc[i][j]);
    }
  }
#pragma unroll
  for (int i = 0; i < 8; i++) {
    float* cp = C + (size_t)(bm + rm + i) * N + bn + rn;
    float4 c0 = {acc[i][0], acc[i][1], acc[i][2], acc[i][3]};
    float4 c1 = {acc[i][4], acc[i][5], acc[i][6], acc[i][7]};
    *(float4*)cp = c0;
    *(float4*)(cp + 4) = c1;
  }
}

// ---------------------------------------------------------------------------
// abq[row,h,0] = sigmoid(x@Wa^T + ba), abq[row,h,1] = softplus(x@Wb^T+bb)*K^-.5
// (slot 2 = k.q filled later by norm_qk; slot 3 unused)
// ---------------------------------------------------------------------------
__global__ __launch_bounds__(64) void ab_proj(const float* __restrict__ x,
                                              const float* __restrict__ Wa,
                                              const float* __restrict__ ba,
                                              const float* __restrict__ Wb,
                                              const float* __restrict__ bb,
                                              float* __restrict__ abq) {
  const int row = blockIdx.x;
  const int g = blockIdx.y;
  const int h0 = (g & 1) * 8;
  const bool isA = (g < 2);
  const float* W = isA ? Wa : Wb;
  const int lane = threadIdx.x;
  const float* xr = x + (size_t)row * DD;
  float acc[8];
#pragma unroll
  for (int j = 0; j < 8; j++) acc[j] = 0.f;
  for (int d = lane; d < DD; d += 64) {
    const float xv = xr[d];
#pragma unroll
    for (int j = 0; j < 8; j++)
      acc[j] = fmaf(xv, W[(size_t)(h0 + j) * DD + d], acc[j]);
  }
#pragma unroll
  for (int j = 0; j < 8; j++) {
#pragma unroll
    for (int off = 32; off > 0; off >>= 1) acc[j] += __shfl_xor(acc[j], off, 64);
  }
  if (lane == 0) {
    if (isA) {
#pragma unroll
      for (int j = 0; j < 8; j++) {
        const float z = acc[j] + ba[h0 + j];
        abq[((size_t)row * HH + h0 + j) * 4 + 0] = 1.0f / (1.0f + expf(-z));
      }
    } else {
#pragma unroll
      for (int j = 0; j < 8; j++) {
        const float z = acc[j] + bb[h0 + j];
        const float sp = (z > 20.f) ? z : log1pf(expf(z));
        abq[((size_t)row * HH + h0 + j) * 4 + 1] = sp * 0.08838834764831845f;
      }
    }
  }
}

// ---------------------------------------------------------------------------
// l2-normalize q,k (in place) and write kq = dot(qn,kn) to abq slot 2.
// One wave per (b,t,h) vector pair; 4 pairs per 256-block.
// ---------------------------------------------------------------------------
__global__ __launch_bounds__(256) void norm_qk(float* __restrict__ q,
                                               float* __restrict__ k,
                                               float* __restrict__ abq) {
  const int vec = blockIdx.x * 4 + (threadIdx.x >> 6);
  const int l = threadIdx.x & 63;
  float* qp = q + (size_t)vec * 128;
  float* kp = k + (size_t)vec * 128;
  float q0 = qp[l], q1 = qp[l + 64];
  float k0 = kp[l], k1 = kp[l + 64];
  float sq = q0 * q0 + q1 * q1;
  float sk = k0 * k0 + k1 * k1;
#pragma unroll
  for (int off = 32; off > 0; off >>= 1) {
    sq += __shfl_xor(sq, off, 64);
    sk += __shfl_xor(sk, off, 64);
  }
  const float iq = 1.0f / fmaxf(sqrtf(sq), 1e-12f);
  const float ik = 1.0f / fmaxf(sqrtf(sk), 1e-12f);
  q0 *= iq; q1 *= iq; k0 *= ik; k1 *= ik;
  qp[l] = q0; qp[l + 64] = q1;
  kp[l] = k0; kp[l + 64] = k1;
  float pq = q0 * k0 + q1 * k1;
#pragma unroll
  for (int off = 32; off > 0; off >>= 1) pq += __shfl_xor(pq, off, 64);
  if (l == 0) abq[(size_t)vec * 4 + 2] = pq;
}

// ---------------------------------------------------------------------------
// Gated delta rule scan — barrier-free, LDS-free.
// 32 lanes per V-row (4 state floats/thread), 8 rows per 256-block,
// 16 blocks per (b,h) -> grid 512. Depth-2 register prefetch.
// o_t = a*(S_{t-1}.q) + u*(k.q): dk & dq butterflies run in parallel and the
// precomputed kq keeps the o-reduction off the serial chain.
// ---------------------------------------------------------------------------
__global__ __launch_bounds__(256) void scan_kernel(const float* __restrict__ q,
                                                   const float* __restrict__ k,
                                                   const float* __restrict__ v,
                                                   const float* __restrict__ abq,
                                                   float* __restrict__ o) {
  const int bid = blockIdx.x;  // [0,512)
  const int s = bid & 15;      // V-split
  const int bh = bid >> 4;     // [0,32)
  const int h = bh & 15;
  const int b = bh >> 4;
  const int t = threadIdx.x;
  const int rl = t >> 5;  // 0..7 local row
  const int g = t & 31;   // k-group (4 floats)
  const int vrow = s * 8 + rl;

  const size_t base = (size_t)b * TT * 2048 + (size_t)h * KK;
  const size_t abase = ((size_t)b * TT * HH + h) * 4;

  const float* kp = k + base + g * 4;
  const float* qp = q + base + g * 4;
  const float* vp = v + base + vrow;
  const float* ap = abq + abase;
  float* op = o + base + vrow;

  float S0 = 0.f, S1 = 0.f, S2 = 0.f, S3 = 0.f;

  float4 kA = *(const float4*)kp;
  float4 qA = *(const float4*)qp;
  float vA = *vp;
  float4 aA = *(const float4*)ap;
  float4 kB = *(const float4*)(kp + 2048);
  float4 qB = *(const float4*)(qp + 2048);
  float vB = *(vp + 2048);
  float4 aB = *(const float4*)(ap + 64);

#define SCAN_STEP(kf, qf, vf, af)                                          \
  {                                                                        \
    float dk = fmaf(S0, kf.x, fmaf(S1, kf.y, fmaf(S2, kf.z, S3 * kf.w)));  \
    float dq = fmaf(S0, qf.x, fmaf(S1, qf.y, fmaf(S2, qf.z, S3 * qf.w)));  \
    dk += __shfl_xor(dk, 1, 64);  dq += __shfl_xor(dq, 1, 64);             \
    dk += __shfl_xor(dk, 2, 64);  dq += __shfl_xor(dq, 2, 64);             \
    dk += __shfl_xor(dk, 4, 64);  dq += __shfl_xor(dq, 4, 64);             \
    dk += __shfl_xor(dk, 8, 64);  dq += __shfl_xor(dq, 8, 64);             \
    dk += __shfl_xor(dk, 16, 64); dq += __shfl_xor(dq, 16, 64);            \
    const float u = af.y * (vf - af.x * dk);                               \
    const float oo = fmaf(af.x, dq, u * af.z);                             \
    S0 = fmaf(af.x, S0, u * kf.x);                                         \
    S1 = fmaf(af.x, S1, u * kf.y);                                         \
    S2 = fmaf(af.x, S2, u * kf.z);                                         \
    S3 = fmaf(af.x, S3, u * kf.w);                                         \
    if (g == 0) *op = oo;                                                  \
  }

  for (int tt = 0; tt < TT; tt += 2) {
    // even step: consume A, prefetch tt+2 into A (reads past end stay in ws)
    {
      const float4 kf = kA, qf = qA, af = aA;
      const float vf = vA;
      kA = *(const float4*)(kp + 4096);
      qA = *(const float4*)(qp + 4096);
      vA = *(vp + 4096);
      aA = *(const float4*)(ap + 128);
      SCAN_STEP(kf, qf, vf, af);
    }
    kp += 2048; qp += 2048; vp += 2048; ap += 64; op += 2048;
    // odd step: consume B, prefetch tt+3 into B
    {
      const float4 kf = kB, qf = qB, af = aB;
      const float vf = vB;
      kB = *(const float4*)(kp + 4096);
      qB = *(const float4*)(qp + 4096);
      vB = *(vp + 4096);
      aB = *(const float4*)(ap + 128);
      SCAN_STEP(kf, qf, vf, af);
    }
    kp += 2048; qp += 2048; vp += 2048; ap += 64; op += 2048;
  }
#undef SCAN_STEP
}

// ---------------------------------------------------------------------------
extern "C" void kernel_launch(void* const* d_in, const int* in_sizes, int n_in,
                              void* d_out, int out_size, void* d_ws,
                              size_t ws_size, hipStream_t stream) {
  const float* x = (const float*)d_in[0];
  const float* Wq = (const float*)d_in[1];
  const float* Wk = (const float*)d_in[2];
  const float* Wv = (const float*)d_in[3];
  const float* Wa = (const float*)d_in[4];
  const float* ba = (const float*)d_in[5];
  const float* Wb = (const float*)d_in[6];
  const float* bb = (const float*)d_in[7];
  float* out = (float*)d_out;
  float* ws = (float*)d_ws;

  const size_t PROJ = (size_t)BB * TT * HH * KK;  // 8,388,608 floats
  float* qw = ws;                                 // [B*T, H*K]
  float* kw = ws + PROJ;
  float* vw = ws + 2 * PROJ;
  float* abq = ws + 3 * PROJ;  // [B*T, H, 4] = {alpha, beta, kq, pad}
  // + prefetch slack past abq end; total ~97.3 MiB

  const int M = BB * TT;  // 4096
  const int N = HH * KK;  // 2048
  dim3 gg(N / 128, M / 128, 3);
  gemm_nt3<<<gg, 256, 0, stream>>>(x, Wq, Wk, Wv, qw, M, N, DD);
  ab_proj<<<dim3(M, 4), 64, 0, stream>>>(x, Wa, ba, Wb, bb, abq);
  norm_qk<<<(BB * TT * HH) / 4, 256, 0, stream>>>(qw, kw, abq);
  scan_kernel<<<BB * HH * 16, 256, 0, stream>>>(qw, kw, vw, abq, out);
}

// Round 3
// 2051.355 us; speedup vs baseline: 1.6643x; 1.2617x over previous
//
#include <hip/hip_runtime.h>
#include <math.h>

#define BB 2
#define TT 2048
#define DD 2048
#define HH 16
#define KK 128
#define VV 128

// ---------------------------------------------------------------------------
// C[M,N] = A[M,Kd] * W[N,Kd]^T  (fp32, 128x128 tile, 8x8 microtile)
// blockIdx.z selects which of the 3 weight matrices / output slabs.
// ---------------------------------------------------------------------------
__global__ __launch_bounds__(256) void gemm_nt3(const float* __restrict__ A,
                                                const float* __restrict__ W0,
                                                const float* __restrict__ W1,
                                                const float* __restrict__ W2,
                                                float* __restrict__ Cbase,
                                                int M, int N, int Kd) {
  __shared__ float As[8][128];
  __shared__ float Bs[8][128];
  const int z = blockIdx.z;
  const float* W = (z == 0) ? W0 : (z == 1) ? W1 : W2;
  float* C = Cbase + (size_t)z * M * N;
  const int tid = threadIdx.x;
  const int bm = blockIdx.y * 128;
  const int bn = blockIdx.x * 128;
  const int lrow = tid >> 1;       // 0..127
  const int lcol = (tid & 1) * 4;  // 0 or 4
  const int rm = (tid >> 4) * 8;
  const int rn = (tid & 15) * 8;
  const float* Ap = A + (size_t)(bm + lrow) * Kd + lcol;
  const float* Wp = W + (size_t)(bn + lrow) * Kd + lcol;
  float acc[8][8];
#pragma unroll
  for (int i = 0; i < 8; i++)
#pragma unroll
    for (int j = 0; j < 8; j++) acc[i][j] = 0.f;

  float4 av = *(const float4*)Ap;
  float4 wv = *(const float4*)Wp;
  for (int d0 = 0; d0 < Kd; d0 += 8) {
    __syncthreads();
    As[lcol + 0][lrow] = av.x;
    As[lcol + 1][lrow] = av.y;
    As[lcol + 2][lrow] = av.z;
    As[lcol + 3][lrow] = av.w;
    Bs[lcol + 0][lrow] = wv.x;
    Bs[lcol + 1][lrow] = wv.y;
    Bs[lcol + 2][lrow] = wv.z;
    Bs[lcol + 3][lrow] = wv.w;
    __syncthreads();
    if (d0 + 8 < Kd) {  // prefetch next slab while computing this one
      av = *(const float4*)(Ap + d0 + 8);
      wv = *(const float4*)(Wp + d0 + 8);
    }
#pragma unroll
    for (int kk = 0; kk < 8; kk++) {
      const float4 a0 = *(const float4*)&As[kk][rm];
      const float4 a1 = *(const float4*)&As[kk][rm + 4];
      const float4 b0 = *(const float4*)&Bs[kk][rn];
      const float4 b1 = *(const float4*)&Bs[kk][rn + 4];
      const float ar[8] = {a0.x, a0.y, a0.z, a0.w, a1.x, a1.y, a1.z, a1.w};
      const float br[8] = {b0.x, b0.y, b0.z, b0.w, b1.x, b1.y, b1.z, b1.w};
#pragma unroll
      for (int i = 0; i < 8; i++)
#pragma unroll
        for (int j = 0; j < 8; j++) acc[i][j] = fmaf(ar[i], br[j], acc[i][j]);
    }
  }
#pragma unroll
  for (int i = 0; i < 8; i++) {
    float* cp = C + (size_t)(bm + rm + i) * N + bn + rn;
    float4 c0 = {acc[i][0], acc[i][1], acc[i][2], acc[i][3]};
    float4 c1 = {acc[i][4], acc[i][5], acc[i][6], acc[i][7]};
    *(float4*)cp = c0;
    *(float4*)(cp + 4) = c1;
  }
}

// ---------------------------------------------------------------------------
// abq[row,h,0] = sigmoid(x@Wa^T + ba), abq[row,h,1] = softplus(x@Wb^T+bb)*K^-.5
// (slot 2 = k.q filled later by norm_qk; slot 3 unused)
// ---------------------------------------------------------------------------
__global__ __launch_bounds__(64) void ab_proj(const float* __restrict__ x,
                                              const float* __restrict__ Wa,
                                              const float* __restrict__ ba,
                                              const float* __restrict__ Wb,
                                              const float* __restrict__ bb,
                                              float* __restrict__ abq) {
  const int row = blockIdx.x;
  const int g = blockIdx.y;
  const int h0 = (g & 1) * 8;
  const bool isA = (g < 2);
  const float* W = isA ? Wa : Wb;
  const int lane = threadIdx.x;
  const float* xr = x + (size_t)row * DD;
  float acc[8];
#pragma unroll
  for (int j = 0; j < 8; j++) acc[j] = 0.f;
  for (int d = lane; d < DD; d += 64) {
    const float xv = xr[d];
#pragma unroll
    for (int j = 0; j < 8; j++)
      acc[j] = fmaf(xv, W[(size_t)(h0 + j) * DD + d], acc[j]);
  }
#pragma unroll
  for (int j = 0; j < 8; j++) {
#pragma unroll
    for (int off = 32; off > 0; off >>= 1) acc[j] += __shfl_xor(acc[j], off, 64);
  }
  if (lane == 0) {
    if (isA) {
#pragma unroll
      for (int j = 0; j < 8; j++) {
        const float z = acc[j] + ba[h0 + j];
        abq[((size_t)row * HH + h0 + j) * 4 + 0] = 1.0f / (1.0f + expf(-z));
      }
    } else {
#pragma unroll
      for (int j = 0; j < 8; j++) {
        const float z = acc[j] + bb[h0 + j];
        const float sp = (z > 20.f) ? z : log1pf(expf(z));
        abq[((size_t)row * HH + h0 + j) * 4 + 1] = sp * 0.08838834764831845f;
      }
    }
  }
}

// ---------------------------------------------------------------------------
// l2-normalize q,k (in place) and write kq = dot(qn,kn) to abq slot 2.
// ---------------------------------------------------------------------------
__global__ __launch_bounds__(256) void norm_qk(float* __restrict__ q,
                                               float* __restrict__ k,
                                               float* __restrict__ abq) {
  const int vec = blockIdx.x * 4 + (threadIdx.x >> 6);
  const int l = threadIdx.x & 63;
  float* qp = q + (size_t)vec * 128;
  float* kp = k + (size_t)vec * 128;
  float q0 = qp[l], q1 = qp[l + 64];
  float k0 = kp[l], k1 = kp[l + 64];
  float sq = q0 * q0 + q1 * q1;
  float sk = k0 * k0 + k1 * k1;
#pragma unroll
  for (int off = 32; off > 0; off >>= 1) {
    sq += __shfl_xor(sq, off, 64);
    sk += __shfl_xor(sk, off, 64);
  }
  const float iq = 1.0f / fmaxf(sqrtf(sq), 1e-12f);
  const float ik = 1.0f / fmaxf(sqrtf(sk), 1e-12f);
  q0 *= iq; q1 *= iq; k0 *= ik; k1 *= ik;
  qp[l] = q0; qp[l + 64] = q1;
  kp[l] = k0; kp[l + 64] = k1;
  float pq = q0 * k0 + q1 * k1;
#pragma unroll
  for (int off = 32; off > 0; off >>= 1) pq += __shfl_xor(pq, off, 64);
  if (l == 0) abq[(size_t)vec * 4 + 2] = pq;
}

// ---------------------------------------------------------------------------
// Gated delta rule scan — barrier-free, LDS-free.
// 32 lanes per V-row (4 state floats/thread), 8 rows per 256-block.
// Grid 512, bid = s*32 + bh so all 16 V-splits of one (b,h) share bid%8
// (same XCD -> k/q/abq served once per XCD from L2, not 16x from HBM).
// Depth-4 rotating register prefetch hides L2 latency.
// 32-lane sum-allreduce: 4 DPP-VALU stages (quad_perm x2, half_mirror,
// mirror — each pairs complementary halves at widths 2/4/8/16) + one
// ds_swizzle xor16 for the 32-wide stage. Exact allreduce, ~half the
// dependent-latency of 5 chained ds_swizzles.
// ---------------------------------------------------------------------------
#define DPP_ADD(x, ctrl)                                                     \
  ((x) + __int_as_float(__builtin_amdgcn_update_dpp(                         \
             0, __float_as_int(x), (ctrl), 0xF, 0xF, true)))
#define SWZ16_ADD(x) \
  ((x) + __int_as_float(__builtin_amdgcn_ds_swizzle(__float_as_int(x), 0x401F)))

__global__ __launch_bounds__(256) void scan_kernel(const float* __restrict__ q,
                                                   const float* __restrict__ k,
                                                   const float* __restrict__ v,
                                                   const float* __restrict__ abq,
                                                   float* __restrict__ o) {
  const int bid = blockIdx.x;  // = s*32 + bh
  const int bh = bid & 31;
  const int s = bid >> 5;      // V-split 0..15
  const int h = bh & 15;
  const int b = bh >> 4;
  const int t = threadIdx.x;
  const int rl = t >> 5;  // 0..7 local row
  const int g = t & 31;   // k-group (4 floats)
  const int vrow = s * 8 + rl;

  const size_t base = (size_t)b * TT * 2048 + (size_t)h * KK;
  const size_t abase = ((size_t)b * TT * HH + h) * 4;

  const float* kp = k + base + g * 4;
  const float* qp = q + base + g * 4;
  const float* vp = v + base + vrow;
  const float* ap = abq + abase;
  float* op = o + base + vrow;

  float S0 = 0.f, S1 = 0.f, S2 = 0.f, S3 = 0.f;

  float4 kf[4], qf[4], af[4];
  float vf[4];
#pragma unroll
  for (int d = 0; d < 4; d++) {
    kf[d] = *(const float4*)(kp + d * 2048);
    qf[d] = *(const float4*)(qp + d * 2048);
    vf[d] = vp[d * 2048];
    af[d] = *(const float4*)(ap + d * 64);
  }

  for (int tt = 0; tt < TT; tt += 4) {
#pragma unroll
    for (int j = 0; j < 4; j++) {
      const float4 kc = kf[j], qc = qf[j], ac = af[j];
      const float vc = vf[j];
      // prefetch step tt+j+4 (reads past the end stay inside ws slabs)
      kf[j] = *(const float4*)(kp + 4 * 2048);
      qf[j] = *(const float4*)(qp + 4 * 2048);
      vf[j] = vp[4 * 2048];
      af[j] = *(const float4*)(ap + 4 * 64);

      float dk = fmaf(S0, kc.x, fmaf(S1, kc.y, fmaf(S2, kc.z, S3 * kc.w)));
      float dq = fmaf(S0, qc.x, fmaf(S1, qc.y, fmaf(S2, qc.z, S3 * qc.w)));
      dk = DPP_ADD(dk, 0xB1);   // quad_perm(1,0,3,2): width-2
      dq = DPP_ADD(dq, 0xB1);
      dk = DPP_ADD(dk, 0x4E);   // quad_perm(2,3,0,1): width-4
      dq = DPP_ADD(dq, 0x4E);
      dk = DPP_ADD(dk, 0x141);  // row_half_mirror: width-8
      dq = DPP_ADD(dq, 0x141);
      dk = DPP_ADD(dk, 0x140);  // row_mirror: width-16
      dq = DPP_ADD(dq, 0x140);
      dk = SWZ16_ADD(dk);       // xor-16 within 32-lane group
      dq = SWZ16_ADD(dq);

      const float u = ac.y * (vc - ac.x * dk);
      const float oo = fmaf(ac.x, dq, u * ac.z);
      S0 = fmaf(ac.x, S0, u * kc.x);
      S1 = fmaf(ac.x, S1, u * kc.y);
      S2 = fmaf(ac.x, S2, u * kc.z);
      S3 = fmaf(ac.x, S3, u * kc.w);
      if (g == 0) *op = oo;

      kp += 2048; qp += 2048; vp += 2048; ap += 64; op += 2048;
    }
  }
}

// ---------------------------------------------------------------------------
extern "C" void kernel_launch(void* const* d_in, const int* in_sizes, int n_in,
                              void* d_out, int out_size, void* d_ws,
                              size_t ws_size, hipStream_t stream) {
  const float* x = (const float*)d_in[0];
  const float* Wq = (const float*)d_in[1];
  const float* Wk = (const float*)d_in[2];
  const float* Wv = (const float*)d_in[3];
  const float* Wa = (const float*)d_in[4];
  const float* ba = (const float*)d_in[5];
  const float* Wb = (const float*)d_in[6];
  const float* bb = (const float*)d_in[7];
  float* out = (float*)d_out;
  float* ws = (float*)d_ws;

  const size_t PROJ = (size_t)BB * TT * HH * KK;  // 8,388,608 floats
  float* qw = ws;                                 // [B*T, H*K]
  float* kw = ws + PROJ;
  float* vw = ws + 2 * PROJ;
  float* abq = ws + 3 * PROJ;  // [B*T, H, 4] = {alpha, beta, kq, pad}

  const int M = BB * TT;  // 4096
  const int N = HH * KK;  // 2048
  dim3 gg(N / 128, M / 128, 3);
  gemm_nt3<<<gg, 256, 0, stream>>>(x, Wq, Wk, Wv, qw, M, N, DD);
  ab_proj<<<dim3(M, 4), 64, 0, stream>>>(x, Wa, ba, Wb, bb, abq);
  norm_qk<<<(BB * TT * HH) / 4, 256, 0, stream>>>(qw, kw, abq);
  scan_kernel<<<BB * HH * 16, 256, 0, stream>>>(qw, kw, vw, abq, out);
}

// Round 4
// 1096.440 us; speedup vs baseline: 3.1137x; 1.8709x over previous
//
#include <hip/hip_runtime.h>
#include <math.h>

#define BB 2
#define TT 2048
#define DD 2048
#define HH 16
#define KK 128

typedef _Float16 h4 __attribute__((ext_vector_type(4)));
typedef _Float16 v8h __attribute__((ext_vector_type(8)));
typedef float v4f __attribute__((ext_vector_type(4)));

// ---------------------------------------------------------------------------
// FALLBACK fp32 GEMM (proven round-3 path) — used only if ws is too small
// for the f16 split buffers.
// ---------------------------------------------------------------------------
__global__ __launch_bounds__(256) void gemm_nt3(const float* __restrict__ A,
                                                const float* __restrict__ W0,
                                                const float* __restrict__ W1,
                                                const float* __restrict__ W2,
                                                float* __restrict__ Cbase,
                                                int M, int N, int Kd) {
  __shared__ float As[8][128];
  __shared__ float Bs[8][128];
  const int z = blockIdx.z;
  const float* W = (z == 0) ? W0 : (z == 1) ? W1 : W2;
  float* C = Cbase + (size_t)z * M * N;
  const int tid = threadIdx.x;
  const int bm = blockIdx.y * 128;
  const int bn = blockIdx.x * 128;
  const int lrow = tid >> 1;
  const int lcol = (tid & 1) * 4;
  const int rm = (tid >> 4) * 8;
  const int rn = (tid & 15) * 8;
  const float* Ap = A + (size_t)(bm + lrow) * Kd + lcol;
  const float* Wp = W + (size_t)(bn + lrow) * Kd + lcol;
  float acc[8][8];
#pragma unroll
  for (int i = 0; i < 8; i++)
#pragma unroll
    for (int j = 0; j < 8; j++) acc[i][j] = 0.f;
  float4 av = *(const float4*)Ap;
  float4 wv = *(const float4*)Wp;
  for (int d0 = 0; d0 < Kd; d0 += 8) {
    __syncthreads();
    As[lcol + 0][lrow] = av.x; As[lcol + 1][lrow] = av.y;
    As[lcol + 2][lrow] = av.z; As[lcol + 3][lrow] = av.w;
    Bs[lcol + 0][lrow] = wv.x; Bs[lcol + 1][lrow] = wv.y;
    Bs[lcol + 2][lrow] = wv.z; Bs[lcol + 3][lrow] = wv.w;
    __syncthreads();
    if (d0 + 8 < Kd) {
      av = *(const float4*)(Ap + d0 + 8);
      wv = *(const float4*)(Wp + d0 + 8);
    }
#pragma unroll
    for (int kk = 0; kk < 8; kk++) {
      const float4 a0 = *(const float4*)&As[kk][rm];
      const float4 a1 = *(const float4*)&As[kk][rm + 4];
      const float4 b0 = *(const float4*)&Bs[kk][rn];
      const float4 b1 = *(const float4*)&Bs[kk][rn + 4];
      const float ar[8] = {a0.x, a0.y, a0.z, a0.w, a1.x, a1.y, a1.z, a1.w};
      const float br[8] = {b0.x, b0.y, b0.z, b0.w, b1.x, b1.y, b1.z, b1.w};
#pragma unroll
      for (int i = 0; i < 8; i++)
#pragma unroll
        for (int j = 0; j < 8; j++) acc[i][j] = fmaf(ar[i], br[j], acc[i][j]);
    }
  }
#pragma unroll
  for (int i = 0; i < 8; i++) {
    float* cp = C + (size_t)(bm + rm + i) * N + bn + rn;
    float4 c0 = {acc[i][0], acc[i][1], acc[i][2], acc[i][3]};
    float4 c1 = {acc[i][4], acc[i][5], acc[i][6], acc[i][7]};
    *(float4*)cp = c0;
    *(float4*)(cp + 4) = c1;
  }
}

// ---------------------------------------------------------------------------
// Convert: x -> xh + xl (f16 hi/lo split), Wq/Wk/Wv -> Wf (single f16).
// One float4 per thread; h4 (8 B) vector stores.
// ---------------------------------------------------------------------------
__global__ __launch_bounds__(256) void convert_f16(
    const float* __restrict__ x, const float* __restrict__ Wq,
    const float* __restrict__ Wk, const float* __restrict__ Wv,
    _Float16* __restrict__ xh, _Float16* __restrict__ xl,
    _Float16* __restrict__ Wf) {
  const size_t N4X = (size_t)BB * TT * DD / 4;       // 2^21
  const size_t N4W = (size_t)(HH * KK) * DD / 4;     // 2^20
  const size_t i = (size_t)blockIdx.x * 256 + threadIdx.x;
  if (i < N4X) {
    const float4 v = ((const float4*)x)[i];
    h4 hi, lo;
    hi.x = (_Float16)v.x; hi.y = (_Float16)v.y;
    hi.z = (_Float16)v.z; hi.w = (_Float16)v.w;
    lo.x = (_Float16)(v.x - (float)hi.x);
    lo.y = (_Float16)(v.y - (float)hi.y);
    lo.z = (_Float16)(v.z - (float)hi.z);
    lo.w = (_Float16)(v.w - (float)hi.w);
    ((h4*)xh)[i] = hi;
    ((h4*)xl)[i] = lo;
  } else {
    const size_t j = i - N4X;
    const float* Ws = (j < N4W) ? Wq : (j < 2 * N4W) ? Wk : Wv;
    const size_t jj = (j < N4W) ? j : (j < 2 * N4W) ? (j - N4W) : (j - 2 * N4W);
    const float4 v = ((const float4*)Ws)[jj];
    h4 hi;
    hi.x = (_Float16)v.x; hi.y = (_Float16)v.y;
    hi.z = (_Float16)v.z; hi.w = (_Float16)v.w;
    ((h4*)Wf)[j] = hi;
  }
}

// ---------------------------------------------------------------------------
// MFMA GEMM: C[z][M=4096][N=2048] = xh*W[z]^T + xl*W[z]^T  (f16 in, fp32 out)
// m97 structure: 128x128 tile, BK=32, global_load_lds width=16,
// 16x16x32 f16 MFMA, 4 waves = 2x2 of 64x64, 4x4 frags/wave.
// ---------------------------------------------------------------------------
#define GLDS(gp, lp)                                              \
  __builtin_amdgcn_global_load_lds(                               \
      (const __attribute__((address_space(1))) void*)(gp),        \
      (__attribute__((address_space(3))) void*)(lp), 16, 0, 0)

__global__ __launch_bounds__(256) void gemm_mfma(
    const _Float16* __restrict__ xh, const _Float16* __restrict__ xl,
    const _Float16* __restrict__ Wf, float* __restrict__ Cbase) {
  __shared__ float4 lraw[1536];  // 24 KB = Ah(4096 f16) | Al | Bs
  _Float16* Ah = (_Float16*)lraw;
  _Float16* Al = Ah + 4096;
  _Float16* Bs = Al + 4096;

  const int z = blockIdx.z;
  const _Float16* W = Wf + (size_t)z * DD * (HH * KK);
  float* C = Cbase + (size_t)z * (BB * TT) * (HH * KK);

  const int tid = threadIdx.x;
  const int w = tid >> 6;
  const int lane = tid & 63;
  const int bm = blockIdx.y * 128;
  const int bn = blockIdx.x * 128;
  const int wm = (w & 1) * 64;
  const int wn = (w >> 1) * 64;
  const int m16 = lane & 15;
  const int quad = lane >> 4;

  // staging: inst j covers rows j*64..j*64+63 of the 128x32 tile;
  // thread tid -> row (tid>>2), 16B granule (tid&3); LDS elem offset tid*8.
  const _Float16* gAh = xh + (size_t)(bm + (tid >> 2)) * DD + (tid & 3) * 8;
  const _Float16* gAl = xl + (size_t)(bm + (tid >> 2)) * DD + (tid & 3) * 8;
  const _Float16* gB = W + (size_t)(bn + (tid >> 2)) * DD + (tid & 3) * 8;
  const int lb = w * 512;  // wave-uniform LDS base (f16 elems), lane adds l*8

  v4f acc[4][4];
#pragma unroll
  for (int i = 0; i < 4; i++)
#pragma unroll
    for (int j = 0; j < 4; j++) acc[i][j] = (v4f){0.f, 0.f, 0.f, 0.f};

  for (int d0 = 0; d0 < DD; d0 += 32) {
    GLDS(gAh + d0, Ah + lb);
    GLDS(gAh + d0 + 64 * DD, Ah + 2048 + lb);
    GLDS(gAl + d0, Al + lb);
    GLDS(gAl + d0 + 64 * DD, Al + 2048 + lb);
    GLDS(gB + d0, Bs + lb);
    GLDS(gB + d0 + 64 * DD, Bs + 2048 + lb);
    __syncthreads();  // barrier drains vmcnt -> staged data visible
    v8h ah[4], al[4], bw[4];
#pragma unroll
    for (int i = 0; i < 4; i++) {
      ah[i] = *(const v8h*)&Ah[(wm + i * 16 + m16) * 32 + quad * 8];
      al[i] = *(const v8h*)&Al[(wm + i * 16 + m16) * 32 + quad * 8];
      bw[i] = *(const v8h*)&Bs[(wn + i * 16 + m16) * 32 + quad * 8];
    }
#pragma unroll
    for (int mi = 0; mi < 4; mi++)
#pragma unroll
      for (int ni = 0; ni < 4; ni++) {
        acc[mi][ni] = __builtin_amdgcn_mfma_f32_16x16x32_f16(ah[mi], bw[ni],
                                                             acc[mi][ni], 0, 0, 0);
        acc[mi][ni] = __builtin_amdgcn_mfma_f32_16x16x32_f16(al[mi], bw[ni],
                                                             acc[mi][ni], 0, 0, 0);
      }
    __syncthreads();
  }
  // epilogue: D[row=quad*4+r][col=m16] per 16x16 frag
#pragma unroll
  for (int mi = 0; mi < 4; mi++) {
#pragma unroll
    for (int r = 0; r < 4; r++) {
      float* cp =
          C + (size_t)(bm + wm + mi * 16 + quad * 4 + r) * (HH * KK) + bn + wn + m16;
#pragma unroll
      for (int ni = 0; ni < 4; ni++) cp[ni * 16] = acc[mi][ni][r];
    }
  }
}

// ---------------------------------------------------------------------------
// alpha/beta projections (unchanged)
// ---------------------------------------------------------------------------
__global__ __launch_bounds__(64) void ab_proj(const float* __restrict__ x,
                                              const float* __restrict__ Wa,
                                              const float* __restrict__ ba,
                                              const float* __restrict__ Wb,
                                              const float* __restrict__ bb,
                                              float* __restrict__ abq) {
  const int row = blockIdx.x;
  const int g = blockIdx.y;
  const int h0 = (g & 1) * 8;
  const bool isA = (g < 2);
  const float* W = isA ? Wa : Wb;
  const int lane = threadIdx.x;
  const float* xr = x + (size_t)row * DD;
  float acc[8];
#pragma unroll
  for (int j = 0; j < 8; j++) acc[j] = 0.f;
  for (int d = lane; d < DD; d += 64) {
    const float xv = xr[d];
#pragma unroll
    for (int j = 0; j < 8; j++)
      acc[j] = fmaf(xv, W[(size_t)(h0 + j) * DD + d], acc[j]);
  }
#pragma unroll
  for (int j = 0; j < 8; j++) {
#pragma unroll
    for (int off = 32; off > 0; off >>= 1) acc[j] += __shfl_xor(acc[j], off, 64);
  }
  if (lane == 0) {
    if (isA) {
#pragma unroll
      for (int j = 0; j < 8; j++) {
        const float z = acc[j] + ba[h0 + j];
        abq[((size_t)row * HH + h0 + j) * 4 + 0] = 1.0f / (1.0f + expf(-z));
      }
    } else {
#pragma unroll
      for (int j = 0; j < 8; j++) {
        const float z = acc[j] + bb[h0 + j];
        const float sp = (z > 20.f) ? z : log1pf(expf(z));
        abq[((size_t)row * HH + h0 + j) * 4 + 1] = sp * 0.08838834764831845f;
      }
    }
  }
}

// ---------------------------------------------------------------------------
// l2-normalize q,k in place; kq = dot(qn,kn) -> abq slot 2 (unchanged)
// ---------------------------------------------------------------------------
__global__ __launch_bounds__(256) void norm_qk(float* __restrict__ q,
                                               float* __restrict__ k,
                                               float* __restrict__ abq) {
  const int vec = blockIdx.x * 4 + (threadIdx.x >> 6);
  const int l = threadIdx.x & 63;
  float* qp = q + (size_t)vec * 128;
  float* kp = k + (size_t)vec * 128;
  float q0 = qp[l], q1 = qp[l + 64];
  float k0 = kp[l], k1 = kp[l + 64];
  float sq = q0 * q0 + q1 * q1;
  float sk = k0 * k0 + k1 * k1;
#pragma unroll
  for (int off = 32; off > 0; off >>= 1) {
    sq += __shfl_xor(sq, off, 64);
    sk += __shfl_xor(sk, off, 64);
  }
  const float iq = 1.0f / fmaxf(sqrtf(sq), 1e-12f);
  const float ik = 1.0f / fmaxf(sqrtf(sk), 1e-12f);
  q0 *= iq; q1 *= iq; k0 *= ik; k1 *= ik;
  qp[l] = q0; qp[l + 64] = q1;
  kp[l] = k0; kp[l + 64] = k1;
  float pq = q0 * k0 + q1 * k1;
#pragma unroll
  for (int off = 32; off > 0; off >>= 1) pq += __shfl_xor(pq, off, 64);
  if (l == 0) abq[(size_t)vec * 4 + 2] = pq;
}

// ---------------------------------------------------------------------------
// Scan: barrier-free, LDS-free, XCD-local grid, DPP allreduce.
// NEW: depth-8 register prefetch PINNED with sched_barrier(0) so the
// compiler cannot sink the loads to their use (round-3 VGPR=28 proved it
// was doing exactly that). Epilogue unroll removes all overreads.
// ---------------------------------------------------------------------------
#define DPP_ADD(x, ctrl)                                                     \
  ((x) + __int_as_float(__builtin_amdgcn_update_dpp(                         \
             0, __float_as_int(x), (ctrl), 0xF, 0xF, true)))
#define SWZ16_ADD(x) \
  ((x) + __int_as_float(__builtin_amdgcn_ds_swizzle(__float_as_int(x), 0x401F)))

#define SCAN_STEP(kc, qc, vc, ac)                                          \
  {                                                                        \
    float dk = fmaf(S0, kc.x, fmaf(S1, kc.y, fmaf(S2, kc.z, S3 * kc.w)));  \
    float dq = fmaf(S0, qc.x, fmaf(S1, qc.y, fmaf(S2, qc.z, S3 * qc.w)));  \
    dk = DPP_ADD(dk, 0xB1);  dq = DPP_ADD(dq, 0xB1);                       \
    dk = DPP_ADD(dk, 0x4E);  dq = DPP_ADD(dq, 0x4E);                       \
    dk = DPP_ADD(dk, 0x141); dq = DPP_ADD(dq, 0x141);                      \
    dk = DPP_ADD(dk, 0x140); dq = DPP_ADD(dq, 0x140);                      \
    dk = SWZ16_ADD(dk);      dq = SWZ16_ADD(dq);                           \
    const float u = ac.y * (vc - ac.x * dk);                               \
    const float oo = fmaf(ac.x, dq, u * ac.z);                             \
    S0 = fmaf(ac.x, S0, u * kc.x);                                         \
    S1 = fmaf(ac.x, S1, u * kc.y);                                         \
    S2 = fmaf(ac.x, S2, u * kc.z);                                         \
    S3 = fmaf(ac.x, S3, u * kc.w);                                         \
    if (g == 0) *op = oo;                                                  \
  }

__global__ __launch_bounds__(256) void scan_kernel(const float* __restrict__ q,
                                                   const float* __restrict__ k,
                                                   const float* __restrict__ v,
                                                   const float* __restrict__ abq,
                                                   float* __restrict__ o) {
  const int bid = blockIdx.x;  // = s*32 + bh  (V-splits of a (b,h) share XCD)
  const int bh = bid & 31;
  const int s = bid >> 5;
  const int h = bh & 15;
  const int b = bh >> 4;
  const int t = threadIdx.x;
  const int rl = t >> 5;
  const int g = t & 31;
  const int vrow = s * 8 + rl;

  const size_t base = (size_t)b * TT * 2048 + (size_t)h * KK;
  const size_t abase = ((size_t)b * TT * HH + h) * 4;

  const float* kp = k + base + g * 4;
  const float* qp = q + base + g * 4;
  const float* vp = v + base + vrow;
  const float* ap = abq + abase;
  float* op = o + base + vrow;

  float S0 = 0.f, S1 = 0.f, S2 = 0.f, S3 = 0.f;

  float4 kf[8], qf[8], af[8];
  float vf[8];
#pragma unroll
  for (int d = 0; d < 8; d++) {
    kf[d] = *(const float4*)(kp + d * 2048);
    qf[d] = *(const float4*)(qp + d * 2048);
    vf[d] = vp[d * 2048];
    af[d] = *(const float4*)(ap + d * 64);
  }

  for (int tt = 0; tt < TT - 8; tt += 8) {
#pragma unroll
    for (int j = 0; j < 8; j++) {
      const float4 kc = kf[j], qc = qf[j], ac = af[j];
      const float vc = vf[j];
      // prefetch step tt+j+8 (in bounds: max index = TT-1)
      kf[j] = *(const float4*)(kp + 8 * 2048);
      qf[j] = *(const float4*)(qp + 8 * 2048);
      vf[j] = vp[8 * 2048];
      af[j] = *(const float4*)(ap + 8 * 64);
      __builtin_amdgcn_sched_barrier(0);  // pin loads above the compute
      SCAN_STEP(kc, qc, vc, ac);
      kp += 2048; qp += 2048; vp += 2048; ap += 64; op += 2048;
    }
  }
  // final 8 steps: consume, no prefetch
#pragma unroll
  for (int j = 0; j < 8; j++) {
    const float4 kc = kf[j], qc = qf[j], ac = af[j];
    const float vc = vf[j];
    SCAN_STEP(kc, qc, vc, ac);
    op += 2048;
  }
}

// ---------------------------------------------------------------------------
extern "C" void kernel_launch(void* const* d_in, const int* in_sizes, int n_in,
                              void* d_out, int out_size, void* d_ws,
                              size_t ws_size, hipStream_t stream) {
  const float* x = (const float*)d_in[0];
  const float* Wq = (const float*)d_in[1];
  const float* Wk = (const float*)d_in[2];
  const float* Wv = (const float*)d_in[3];
  const float* Wa = (const float*)d_in[4];
  const float* ba = (const float*)d_in[5];
  const float* Wb = (const float*)d_in[6];
  const float* bb = (const float*)d_in[7];
  float* out = (float*)d_out;
  float* ws = (float*)d_ws;

  const size_t PROJ = (size_t)BB * TT * HH * KK;  // 8,388,608
  const size_t NABQ = (size_t)BB * TT * HH * 4;   // 262,144
  float* qw = ws;
  float* kw = ws + PROJ;
  float* vw = ws + 2 * PROJ;
  float* abq = ws + 3 * PROJ;
  _Float16* xh = (_Float16*)(abq + NABQ);
  _Float16* xl = xh + (size_t)BB * TT * DD;          // 8,388,608 f16
  _Float16* Wf = xl + (size_t)BB * TT * DD;          // 12,582,912 f16
  const size_t NEED = (3 * PROJ + NABQ) * 4 +
                      ((size_t)BB * TT * DD * 2 + 3 * (size_t)(HH * KK) * DD) * 2;

  const int M = BB * TT;  // 4096
  const int N = HH * KK;  // 2048
  if (ws_size >= NEED) {
    const int cgrid = (int)(((size_t)BB * TT * DD / 4 + 3 * (size_t)N * DD / 4) / 256);
    convert_f16<<<cgrid, 256, 0, stream>>>(x, Wq, Wk, Wv, xh, xl, Wf);
    gemm_mfma<<<dim3(N / 128, M / 128, 3), 256, 0, stream>>>(xh, xl, Wf, qw);
  } else {
    gemm_nt3<<<dim3(N / 128, M / 128, 3), 256, 0, stream>>>(x, Wq, Wk, Wv, qw,
                                                            M, N, DD);
  }
  ab_proj<<<dim3(M, 4), 64, 0, stream>>>(x, Wa, ba, Wb, bb, abq);
  norm_qk<<<(BB * TT * HH) / 4, 256, 0, stream>>>(qw, kw, abq);
  scan_kernel<<<BB * HH * 16, 256, 0, stream>>>(qw, kw, vw, abq, out);
}

// Round 5
// 873.935 us; speedup vs baseline: 3.9065x; 1.2546x over previous
//
#include <hip/hip_runtime.h>
#include <math.h>

#define BB 2
#define TT 2048
#define DD 2048
#define HH 16
#define KK 128

typedef _Float16 h4 __attribute__((ext_vector_type(4)));
typedef _Float16 v8h __attribute__((ext_vector_type(8)));
typedef float v4f __attribute__((ext_vector_type(4)));

// ---------------------------------------------------------------------------
// FALLBACK fp32 GEMM — used only if ws is too small for the f16 buffers.
// ---------------------------------------------------------------------------
__global__ __launch_bounds__(256) void gemm_nt3(const float* __restrict__ A,
                                                const float* __restrict__ W0,
                                                const float* __restrict__ W1,
                                                const float* __restrict__ W2,
                                                float* __restrict__ Cbase,
                                                int M, int N, int Kd) {
  __shared__ float As[8][128];
  __shared__ float Bs[8][128];
  const int z = blockIdx.z;
  const float* W = (z == 0) ? W0 : (z == 1) ? W1 : W2;
  float* C = Cbase + (size_t)z * M * N;
  const int tid = threadIdx.x;
  const int bm = blockIdx.y * 128;
  const int bn = blockIdx.x * 128;
  const int lrow = tid >> 1;
  const int lcol = (tid & 1) * 4;
  const int rm = (tid >> 4) * 8;
  const int rn = (tid & 15) * 8;
  const float* Ap = A + (size_t)(bm + lrow) * Kd + lcol;
  const float* Wp = W + (size_t)(bn + lrow) * Kd + lcol;
  float acc[8][8];
#pragma unroll
  for (int i = 0; i < 8; i++)
#pragma unroll
    for (int j = 0; j < 8; j++) acc[i][j] = 0.f;
  float4 av = *(const float4*)Ap;
  float4 wv = *(const float4*)Wp;
  for (int d0 = 0; d0 < Kd; d0 += 8) {
    __syncthreads();
    As[lcol + 0][lrow] = av.x; As[lcol + 1][lrow] = av.y;
    As[lcol + 2][lrow] = av.z; As[lcol + 3][lrow] = av.w;
    Bs[lcol + 0][lrow] = wv.x; Bs[lcol + 1][lrow] = wv.y;
    Bs[lcol + 2][lrow] = wv.z; Bs[lcol + 3][lrow] = wv.w;
    __syncthreads();
    if (d0 + 8 < Kd) {
      av = *(const float4*)(Ap + d0 + 8);
      wv = *(const float4*)(Wp + d0 + 8);
    }
#pragma unroll
    for (int kk = 0; kk < 8; kk++) {
      const float4 a0 = *(const float4*)&As[kk][rm];
      const float4 a1 = *(const float4*)&As[kk][rm + 4];
      const float4 b0 = *(const float4*)&Bs[kk][rn];
      const float4 b1 = *(const float4*)&Bs[kk][rn + 4];
      const float ar[8] = {a0.x, a0.y, a0.z, a0.w, a1.x, a1.y, a1.z, a1.w};
      const float br[8] = {b0.x, b0.y, b0.z, b0.w, b1.x, b1.y, b1.z, b1.w};
#pragma unroll
      for (int i = 0; i < 8; i++)
#pragma unroll
        for (int j = 0; j < 8; j++) acc[i][j] = fmaf(ar[i], br[j], acc[i][j]);
    }
  }
#pragma unroll
  for (int i = 0; i < 8; i++) {
    float* cp = C + (size_t)(bm + rm + i) * N + bn + rn;
    float4 c0 = {acc[i][0], acc[i][1], acc[i][2], acc[i][3]};
    float4 c1 = {acc[i][4], acc[i][5], acc[i][6], acc[i][7]};
    *(float4*)cp = c0;
    *(float4*)(cp + 4) = c1;
  }
}

// ---------------------------------------------------------------------------
// Convert: x -> xh + xl (f16 hi/lo split), Wq/Wk/Wv -> Wf (single f16).
// ---------------------------------------------------------------------------
__global__ __launch_bounds__(256) void convert_f16(
    const float* __restrict__ x, const float* __restrict__ Wq,
    const float* __restrict__ Wk, const float* __restrict__ Wv,
    _Float16* __restrict__ xh, _Float16* __restrict__ xl,
    _Float16* __restrict__ Wf) {
  const size_t N4X = (size_t)BB * TT * DD / 4;
  const size_t N4W = (size_t)(HH * KK) * DD / 4;
  const size_t i = (size_t)blockIdx.x * 256 + threadIdx.x;
  if (i < N4X) {
    const float4 v = ((const float4*)x)[i];
    h4 hi, lo;
    hi.x = (_Float16)v.x; hi.y = (_Float16)v.y;
    hi.z = (_Float16)v.z; hi.w = (_Float16)v.w;
    lo.x = (_Float16)(v.x - (float)hi.x);
    lo.y = (_Float16)(v.y - (float)hi.y);
    lo.z = (_Float16)(v.z - (float)hi.z);
    lo.w = (_Float16)(v.w - (float)hi.w);
    ((h4*)xh)[i] = hi;
    ((h4*)xl)[i] = lo;
  } else {
    const size_t j = i - N4X;
    const float* Ws = (j < N4W) ? Wq : (j < 2 * N4W) ? Wk : Wv;
    const size_t jj = (j < N4W) ? j : (j < 2 * N4W) ? (j - N4W) : (j - 2 * N4W);
    const float4 v = ((const float4*)Ws)[jj];
    h4 hi;
    hi.x = (_Float16)v.x; hi.y = (_Float16)v.y;
    hi.z = (_Float16)v.z; hi.w = (_Float16)v.w;
    ((h4*)Wf)[j] = hi;
  }
}

// ---------------------------------------------------------------------------
// MFMA GEMM: C[z] = xh*W[z]^T + xl*W[z]^T  (f16 in, fp32 out) — m97 structure
// ---------------------------------------------------------------------------
#define GLDS(gp, lp)                                              \
  __builtin_amdgcn_global_load_lds(                               \
      (const __attribute__((address_space(1))) void*)(gp),        \
      (__attribute__((address_space(3))) void*)(lp), 16, 0, 0)

__global__ __launch_bounds__(256) void gemm_mfma(
    const _Float16* __restrict__ xh, const _Float16* __restrict__ xl,
    const _Float16* __restrict__ Wf, float* __restrict__ Cbase) {
  __shared__ float4 lraw[1536];  // 24 KB = Ah | Al | Bs
  _Float16* Ah = (_Float16*)lraw;
  _Float16* Al = Ah + 4096;
  _Float16* Bs = Al + 4096;

  const int z = blockIdx.z;
  const _Float16* W = Wf + (size_t)z * DD * (HH * KK);
  float* C = Cbase + (size_t)z * (BB * TT) * (HH * KK);

  const int tid = threadIdx.x;
  const int w = tid >> 6;
  const int lane = tid & 63;
  const int bm = blockIdx.y * 128;
  const int bn = blockIdx.x * 128;
  const int wm = (w & 1) * 64;
  const int wn = (w >> 1) * 64;
  const int m16 = lane & 15;
  const int quad = lane >> 4;

  const _Float16* gAh = xh + (size_t)(bm + (tid >> 2)) * DD + (tid & 3) * 8;
  const _Float16* gAl = xl + (size_t)(bm + (tid >> 2)) * DD + (tid & 3) * 8;
  const _Float16* gB = W + (size_t)(bn + (tid >> 2)) * DD + (tid & 3) * 8;
  const int lb = w * 512;

  v4f acc[4][4];
#pragma unroll
  for (int i = 0; i < 4; i++)
#pragma unroll
    for (int j = 0; j < 4; j++) acc[i][j] = (v4f){0.f, 0.f, 0.f, 0.f};

  for (int d0 = 0; d0 < DD; d0 += 32) {
    GLDS(gAh + d0, Ah + lb);
    GLDS(gAh + d0 + 64 * DD, Ah + 2048 + lb);
    GLDS(gAl + d0, Al + lb);
    GLDS(gAl + d0 + 64 * DD, Al + 2048 + lb);
    GLDS(gB + d0, Bs + lb);
    GLDS(gB + d0 + 64 * DD, Bs + 2048 + lb);
    __syncthreads();
    v8h ah[4], al[4], bw[4];
#pragma unroll
    for (int i = 0; i < 4; i++) {
      ah[i] = *(const v8h*)&Ah[(wm + i * 16 + m16) * 32 + quad * 8];
      al[i] = *(const v8h*)&Al[(wm + i * 16 + m16) * 32 + quad * 8];
      bw[i] = *(const v8h*)&Bs[(wn + i * 16 + m16) * 32 + quad * 8];
    }
#pragma unroll
    for (int mi = 0; mi < 4; mi++)
#pragma unroll
      for (int ni = 0; ni < 4; ni++) {
        acc[mi][ni] = __builtin_amdgcn_mfma_f32_16x16x32_f16(ah[mi], bw[ni],
                                                             acc[mi][ni], 0, 0, 0);
        acc[mi][ni] = __builtin_amdgcn_mfma_f32_16x16x32_f16(al[mi], bw[ni],
                                                             acc[mi][ni], 0, 0, 0);
      }
    __syncthreads();
  }
#pragma unroll
  for (int mi = 0; mi < 4; mi++) {
#pragma unroll
    for (int r = 0; r < 4; r++) {
      float* cp =
          C + (size_t)(bm + wm + mi * 16 + quad * 4 + r) * (HH * KK) + bn + wn + m16;
#pragma unroll
      for (int ni = 0; ni < 4; ni++) cp[ni * 16] = acc[mi][ni][r];
    }
  }
}

// ---------------------------------------------------------------------------
// alpha/beta projections (unchanged)
// ---------------------------------------------------------------------------
__global__ __launch_bounds__(64) void ab_proj(const float* __restrict__ x,
                                              const float* __restrict__ Wa,
                                              const float* __restrict__ ba,
                                              const float* __restrict__ Wb,
                                              const float* __restrict__ bb,
                                              float* __restrict__ abq) {
  const int row = blockIdx.x;
  const int g = blockIdx.y;
  const int h0 = (g & 1) * 8;
  const bool isA = (g < 2);
  const float* W = isA ? Wa : Wb;
  const int lane = threadIdx.x;
  const float* xr = x + (size_t)row * DD;
  float acc[8];
#pragma unroll
  for (int j = 0; j < 8; j++) acc[j] = 0.f;
  for (int d = lane; d < DD; d += 64) {
    const float xv = xr[d];
#pragma unroll
    for (int j = 0; j < 8; j++)
      acc[j] = fmaf(xv, W[(size_t)(h0 + j) * DD + d], acc[j]);
  }
#pragma unroll
  for (int j = 0; j < 8; j++) {
#pragma unroll
    for (int off = 32; off > 0; off >>= 1) acc[j] += __shfl_xor(acc[j], off, 64);
  }
  if (lane == 0) {
    if (isA) {
#pragma unroll
      for (int j = 0; j < 8; j++) {
        const float z = acc[j] + ba[h0 + j];
        abq[((size_t)row * HH + h0 + j) * 4 + 0] = 1.0f / (1.0f + expf(-z));
      }
    } else {
#pragma unroll
      for (int j = 0; j < 8; j++) {
        const float z = acc[j] + bb[h0 + j];
        const float sp = (z > 20.f) ? z : log1pf(expf(z));
        abq[((size_t)row * HH + h0 + j) * 4 + 1] = sp * 0.08838834764831845f;
      }
    }
  }
}

// ---------------------------------------------------------------------------
// l2-normalize q,k in place; kq = dot(qn,kn) -> abq slot 2 (unchanged)
// ---------------------------------------------------------------------------
__global__ __launch_bounds__(256) void norm_qk(float* __restrict__ q,
                                               float* __restrict__ k,
                                               float* __restrict__ abq) {
  const int vec = blockIdx.x * 4 + (threadIdx.x >> 6);
  const int l = threadIdx.x & 63;
  float* qp = q + (size_t)vec * 128;
  float* kp = k + (size_t)vec * 128;
  float q0 = qp[l], q1 = qp[l + 64];
  float k0 = kp[l], k1 = kp[l + 64];
  float sq = q0 * q0 + q1 * q1;
  float sk = k0 * k0 + k1 * k1;
#pragma unroll
  for (int off = 32; off > 0; off >>= 1) {
    sq += __shfl_xor(sq, off, 64);
    sk += __shfl_xor(sk, off, 64);
  }
  const float iq = 1.0f / fmaxf(sqrtf(sq), 1e-12f);
  const float ik = 1.0f / fmaxf(sqrtf(sk), 1e-12f);
  q0 *= iq; q1 *= iq; k0 *= ik; k1 *= ik;
  qp[l] = q0; qp[l + 64] = q1;
  kp[l] = k0; kp[l + 64] = k1;
  float pq = q0 * k0 + q1 * k1;
#pragma unroll
  for (int off = 32; off > 0; off >>= 1) pq += __shfl_xor(pq, off, 64);
  if (l == 0) abq[(size_t)vec * 4 + 2] = pq;
}

// ---------------------------------------------------------------------------
// Scan v3: 16-lane row-groups, 8 state floats/thread, ALL-DPP 16-wide
// allreduce (no LDS-pipe op on the critical path). 256 blocks
// (8 V-splits x 32 bh; bid%8 keeps all splits of a bh on one XCD).
// Depth-4 rotating register prefetch pinned with sched_barrier(0).
// Uniform int time-offset keeps address advance on the scalar pipe.
// ---------------------------------------------------------------------------
#define DPP_ADD(x, ctrl)                                                     \
  ((x) + __int_as_float(__builtin_amdgcn_update_dpp(                         \
             0, __float_as_int(x), (ctrl), 0xF, 0xF, true)))

#define SCAN_STEP(kc0, kc1, qc0, qc1, vc, ac, store_ptr)                     \
  {                                                                          \
    float dkA = fmaf(S0, kc0.x, fmaf(S1, kc0.y, fmaf(S2, kc0.z, S3 * kc0.w))); \
    float dkB = fmaf(S4, kc1.x, fmaf(S5, kc1.y, fmaf(S6, kc1.z, S7 * kc1.w))); \
    float dqA = fmaf(S0, qc0.x, fmaf(S1, qc0.y, fmaf(S2, qc0.z, S3 * qc0.w))); \
    float dqB = fmaf(S4, qc1.x, fmaf(S5, qc1.y, fmaf(S6, qc1.z, S7 * qc1.w))); \
    float dk = dkA + dkB;                                                    \
    float dq = dqA + dqB;                                                    \
    dk = DPP_ADD(dk, 0xB1);  dq = DPP_ADD(dq, 0xB1);   /* width 2  */        \
    dk = DPP_ADD(dk, 0x4E);  dq = DPP_ADD(dq, 0x4E);   /* width 4  */        \
    dk = DPP_ADD(dk, 0x141); dq = DPP_ADD(dq, 0x141);  /* width 8  */        \
    dk = DPP_ADD(dk, 0x140); dq = DPP_ADD(dq, 0x140);  /* width 16 */        \
    const float u = ac.y * (vc - ac.x * dk);                                 \
    const float oo = fmaf(ac.x, dq, u * ac.z);                               \
    S0 = fmaf(ac.x, S0, u * kc0.x);                                          \
    S1 = fmaf(ac.x, S1, u * kc0.y);                                          \
    S2 = fmaf(ac.x, S2, u * kc0.z);                                          \
    S3 = fmaf(ac.x, S3, u * kc0.w);                                          \
    S4 = fmaf(ac.x, S4, u * kc1.x);                                          \
    S5 = fmaf(ac.x, S5, u * kc1.y);                                          \
    S6 = fmaf(ac.x, S6, u * kc1.z);                                          \
    S7 = fmaf(ac.x, S7, u * kc1.w);                                          \
    if (g == 0) *(store_ptr) = oo;                                           \
  }

#define PD 4  // prefetch depth

__global__ __launch_bounds__(256) void scan_kernel(const float* __restrict__ q,
                                                   const float* __restrict__ k,
                                                   const float* __restrict__ v,
                                                   const float* __restrict__ abq,
                                                   float* __restrict__ o) {
  const int bid = blockIdx.x;  // = s*32 + bh
  const int bh = bid & 31;
  const int s = bid >> 5;  // 0..7
  const int h = bh & 15;
  const int b = bh >> 4;
  const int tid = threadIdx.x;
  const int w = tid >> 6;
  const int lane = tid & 63;
  const int rg = lane >> 4;  // 0..3 row within wave
  const int g = lane & 15;   // 0..15 k-group (8 floats)
  const int vrow = s * 16 + w * 4 + rg;

  const size_t base = (size_t)b * TT * 2048 + (size_t)h * KK;
  const float* kb = k + base + g * 8;   // per-lane constant part
  const float* qb = q + base + g * 8;
  const float* vb = v + base + vrow;
  const float* ab = abq + ((size_t)b * TT * HH + h) * 4;
  float* ob = o + base + vrow;

  float S0 = 0.f, S1 = 0.f, S2 = 0.f, S3 = 0.f;
  float S4 = 0.f, S5 = 0.f, S6 = 0.f, S7 = 0.f;

  float4 kf0[PD], kf1[PD], qf0[PD], qf1[PD], af[PD];
  float vf[PD];
#pragma unroll
  for (int d = 0; d < PD; d++) {
    kf0[d] = *(const float4*)(kb + d * 2048);
    kf1[d] = *(const float4*)(kb + d * 2048 + 4);
    qf0[d] = *(const float4*)(qb + d * 2048);
    qf1[d] = *(const float4*)(qb + d * 2048 + 4);
    vf[d] = vb[d * 2048];
    af[d] = *(const float4*)(ab + d * 64);
  }

  int off = 0;   // uniform (SGPR) element offset, +2048 per step
  int aoff = 0;  // uniform abq offset, +64 per step
  for (int t0 = 0; t0 < TT - PD; t0 += PD) {
#pragma unroll
    for (int j = 0; j < PD; j++) {
      const float4 kc0 = kf0[j], kc1 = kf1[j];
      const float4 qc0 = qf0[j], qc1 = qf1[j];
      const float4 ac = af[j];
      const float vc = vf[j];
      // prefetch step t0+j+PD
      kf0[j] = *(const float4*)(kb + off + (j + PD) * 2048);
      kf1[j] = *(const float4*)(kb + off + (j + PD) * 2048 + 4);
      qf0[j] = *(const float4*)(qb + off + (j + PD) * 2048);
      qf1[j] = *(const float4*)(qb + off + (j + PD) * 2048 + 4);
      vf[j] = vb[off + (j + PD) * 2048];
      af[j] = *(const float4*)(ab + aoff + (j + PD) * 64);
      __builtin_amdgcn_sched_barrier(0);  // pin loads above the compute
      SCAN_STEP(kc0, kc1, qc0, qc1, vc, ac, ob + off + j * 2048);
    }
    off += PD * 2048;
    aoff += PD * 64;
  }
  // final PD steps: consume only
#pragma unroll
  for (int j = 0; j < PD; j++) {
    const float4 kc0 = kf0[j], kc1 = kf1[j];
    const float4 qc0 = qf0[j], qc1 = qf1[j];
    const float4 ac = af[j];
    const float vc = vf[j];
    SCAN_STEP(kc0, kc1, qc0, qc1, vc, ac, ob + off + j * 2048);
  }
}

// ---------------------------------------------------------------------------
extern "C" void kernel_launch(void* const* d_in, const int* in_sizes, int n_in,
                              void* d_out, int out_size, void* d_ws,
                              size_t ws_size, hipStream_t stream) {
  const float* x = (const float*)d_in[0];
  const float* Wq = (const float*)d_in[1];
  const float* Wk = (const float*)d_in[2];
  const float* Wv = (const float*)d_in[3];
  const float* Wa = (const float*)d_in[4];
  const float* ba = (const float*)d_in[5];
  const float* Wb = (const float*)d_in[6];
  const float* bb = (const float*)d_in[7];
  float* out = (float*)d_out;
  float* ws = (float*)d_ws;

  const size_t PROJ = (size_t)BB * TT * HH * KK;  // 8,388,608
  const size_t NABQ = (size_t)BB * TT * HH * 4;   // 524,288
  float* qw = ws;
  float* kw = ws + PROJ;
  float* vw = ws + 2 * PROJ;
  float* abq = ws + 3 * PROJ;
  _Float16* xh = (_Float16*)(abq + NABQ);
  _Float16* xl = xh + (size_t)BB * TT * DD;
  _Float16* Wf = xl + (size_t)BB * TT * DD;
  const size_t NEED = (3 * PROJ + NABQ) * 4 +
                      ((size_t)BB * TT * DD * 2 + 3 * (size_t)(HH * KK) * DD) * 2;

  const int M = BB * TT;  // 4096
  const int N = HH * KK;  // 2048
  if (ws_size >= NEED) {
    const int cgrid = (int)(((size_t)BB * TT * DD / 4 + 3 * (size_t)N * DD / 4) / 256);
    convert_f16<<<cgrid, 256, 0, stream>>>(x, Wq, Wk, Wv, xh, xl, Wf);
    gemm_mfma<<<dim3(N / 128, M / 128, 3), 256, 0, stream>>>(xh, xl, Wf, qw);
  } else {
    gemm_nt3<<<dim3(N / 128, M / 128, 3), 256, 0, stream>>>(x, Wq, Wk, Wv, qw,
                                                            M, N, DD);
  }
  ab_proj<<<dim3(M, 4), 64, 0, stream>>>(x, Wa, ba, Wb, bb, abq);
  norm_qk<<<(BB * TT * HH) / 4, 256, 0, stream>>>(qw, kw, abq);
  scan_kernel<<<BB * HH * 8, 256, 0, stream>>>(qw, kw, vw, abq, out);
}

// Round 6
// 779.197 us; speedup vs baseline: 4.3815x; 1.1216x over previous
//
#include <hip/hip_runtime.h>
#include <math.h>

#define BB 2
#define TT 2048
#define DD 2048
#define HH 16
#define KK 128

typedef _Float16 h4 __attribute__((ext_vector_type(4)));
typedef _Float16 v8h __attribute__((ext_vector_type(8)));
typedef float v4f __attribute__((ext_vector_type(4)));

// ---------------------------------------------------------------------------
// FALLBACK fp32 GEMM — used only if ws is too small for the f16 buffers.
// ---------------------------------------------------------------------------
__global__ __launch_bounds__(256) void gemm_nt3(const float* __restrict__ A,
                                                const float* __restrict__ W0,
                                                const float* __restrict__ W1,
                                                const float* __restrict__ W2,
                                                float* __restrict__ Cbase,
                                                int M, int N, int Kd) {
  __shared__ float As[8][128];
  __shared__ float Bs[8][128];
  const int z = blockIdx.z;
  const float* W = (z == 0) ? W0 : (z == 1) ? W1 : W2;
  float* C = Cbase + (size_t)z * M * N;
  const int tid = threadIdx.x;
  const int bm = blockIdx.y * 128;
  const int bn = blockIdx.x * 128;
  const int lrow = tid >> 1;
  const int lcol = (tid & 1) * 4;
  const int rm = (tid >> 4) * 8;
  const int rn = (tid & 15) * 8;
  const float* Ap = A + (size_t)(bm + lrow) * Kd + lcol;
  const float* Wp = W + (size_t)(bn + lrow) * Kd + lcol;
  float acc[8][8];
#pragma unroll
  for (int i = 0; i < 8; i++)
#pragma unroll
    for (int j = 0; j < 8; j++) acc[i][j] = 0.f;
  float4 av = *(const float4*)Ap;
  float4 wv = *(const float4*)Wp;
  for (int d0 = 0; d0 < Kd; d0 += 8) {
    __syncthreads();
    As[lcol + 0][lrow] = av.x; As[lcol + 1][lrow] = av.y;
    As[lcol + 2][lrow] = av.z; As[lcol + 3][lrow] = av.w;
    Bs[lcol + 0][lrow] = wv.x; Bs[lcol + 1][lrow] = wv.y;
    Bs[lcol + 2][lrow] = wv.z; Bs[lcol + 3][lrow] = wv.w;
    __syncthreads();
    if (d0 + 8 < Kd) {
      av = *(const float4*)(Ap + d0 + 8);
      wv = *(const float4*)(Wp + d0 + 8);
    }
#pragma unroll
    for (int kk = 0; kk < 8; kk++) {
      const float4 a0 = *(const float4*)&As[kk][rm];
      const float4 a1 = *(const float4*)&As[kk][rm + 4];
      const float4 b0 = *(const float4*)&Bs[kk][rn];
      const float4 b1 = *(const float4*)&Bs[kk][rn + 4];
      const float ar[8] = {a0.x, a0.y, a0.z, a0.w, a1.x, a1.y, a1.z, a1.w};
      const float br[8] = {b0.x, b0.y, b0.z, b0.w, b1.x, b1.y, b1.z, b1.w};
#pragma unroll
      for (int i = 0; i < 8; i++)
#pragma unroll
        for (int j = 0; j < 8; j++) acc[i][j] = fmaf(ar[i], br[j], acc[i][j]);
    }
  }
#pragma unroll
  for (int i = 0; i < 8; i++) {
    float* cp = C + (size_t)(bm + rm + i) * N + bn + rn;
    float4 c0 = {acc[i][0], acc[i][1], acc[i][2], acc[i][3]};
    float4 c1 = {acc[i][4], acc[i][5], acc[i][6], acc[i][7]};
    *(float4*)cp = c0;
    *(float4*)(cp + 4) = c1;
  }
}

// ---------------------------------------------------------------------------
// Convert: x -> xh + xl (f16 hi/lo split), Wq/Wk/Wv -> Wf (single f16).
// ---------------------------------------------------------------------------
__global__ __launch_bounds__(256) void convert_f16(
    const float* __restrict__ x, const float* __restrict__ Wq,
    const float* __restrict__ Wk, const float* __restrict__ Wv,
    _Float16* __restrict__ xh, _Float16* __restrict__ xl,
    _Float16* __restrict__ Wf) {
  const size_t N4X = (size_t)BB * TT * DD / 4;
  const size_t N4W = (size_t)(HH * KK) * DD / 4;
  const size_t i = (size_t)blockIdx.x * 256 + threadIdx.x;
  if (i < N4X) {
    const float4 v = ((const float4*)x)[i];
    h4 hi, lo;
    hi.x = (_Float16)v.x; hi.y = (_Float16)v.y;
    hi.z = (_Float16)v.z; hi.w = (_Float16)v.w;
    lo.x = (_Float16)(v.x - (float)hi.x);
    lo.y = (_Float16)(v.y - (float)hi.y);
    lo.z = (_Float16)(v.z - (float)hi.z);
    lo.w = (_Float16)(v.w - (float)hi.w);
    ((h4*)xh)[i] = hi;
    ((h4*)xl)[i] = lo;
  } else {
    const size_t j = i - N4X;
    const float* Ws = (j < N4W) ? Wq : (j < 2 * N4W) ? Wk : Wv;
    const size_t jj = (j < N4W) ? j : (j < 2 * N4W) ? (j - N4W) : (j - 2 * N4W);
    const float4 v = ((const float4*)Ws)[jj];
    h4 hi;
    hi.x = (_Float16)v.x; hi.y = (_Float16)v.y;
    hi.z = (_Float16)v.z; hi.w = (_Float16)v.w;
    ((h4*)Wf)[j] = hi;
  }
}

// ---------------------------------------------------------------------------
// MFMA GEMM: C[z] = xh*W[z]^T + xl*W[z]^T  (f16 in, fp32 out) — m97 structure
// ---------------------------------------------------------------------------
#define GLDS(gp, lp)                                              \
  __builtin_amdgcn_global_load_lds(                               \
      (const __attribute__((address_space(1))) void*)(gp),        \
      (__attribute__((address_space(3))) void*)(lp), 16, 0, 0)

__global__ __launch_bounds__(256) void gemm_mfma(
    const _Float16* __restrict__ xh, const _Float16* __restrict__ xl,
    const _Float16* __restrict__ Wf, float* __restrict__ Cbase) {
  __shared__ float4 lraw[1536];  // 24 KB = Ah | Al | Bs
  _Float16* Ah = (_Float16*)lraw;
  _Float16* Al = Ah + 4096;
  _Float16* Bs = Al + 4096;

  const int z = blockIdx.z;
  const _Float16* W = Wf + (size_t)z * DD * (HH * KK);
  float* C = Cbase + (size_t)z * (BB * TT) * (HH * KK);

  const int tid = threadIdx.x;
  const int w = tid >> 6;
  const int lane = tid & 63;
  const int bm = blockIdx.y * 128;
  const int bn = blockIdx.x * 128;
  const int wm = (w & 1) * 64;
  const int wn = (w >> 1) * 64;
  const int m16 = lane & 15;
  const int quad = lane >> 4;

  const _Float16* gAh = xh + (size_t)(bm + (tid >> 2)) * DD + (tid & 3) * 8;
  const _Float16* gAl = xl + (size_t)(bm + (tid >> 2)) * DD + (tid & 3) * 8;
  const _Float16* gB = W + (size_t)(bn + (tid >> 2)) * DD + (tid & 3) * 8;
  const int lb = w * 512;

  v4f acc[4][4];
#pragma unroll
  for (int i = 0; i < 4; i++)
#pragma unroll
    for (int j = 0; j < 4; j++) acc[i][j] = (v4f){0.f, 0.f, 0.f, 0.f};

  for (int d0 = 0; d0 < DD; d0 += 32) {
    GLDS(gAh + d0, Ah + lb);
    GLDS(gAh + d0 + 64 * DD, Ah + 2048 + lb);
    GLDS(gAl + d0, Al + lb);
    GLDS(gAl + d0 + 64 * DD, Al + 2048 + lb);
    GLDS(gB + d0, Bs + lb);
    GLDS(gB + d0 + 64 * DD, Bs + 2048 + lb);
    __syncthreads();
    v8h ah[4], al[4], bw[4];
#pragma unroll
    for (int i = 0; i < 4; i++) {
      ah[i] = *(const v8h*)&Ah[(wm + i * 16 + m16) * 32 + quad * 8];
      al[i] = *(const v8h*)&Al[(wm + i * 16 + m16) * 32 + quad * 8];
      bw[i] = *(const v8h*)&Bs[(wn + i * 16 + m16) * 32 + quad * 8];
    }
#pragma unroll
    for (int mi = 0; mi < 4; mi++)
#pragma unroll
      for (int ni = 0; ni < 4; ni++) {
        acc[mi][ni] = __builtin_amdgcn_mfma_f32_16x16x32_f16(ah[mi], bw[ni],
                                                             acc[mi][ni], 0, 0, 0);
        acc[mi][ni] = __builtin_amdgcn_mfma_f32_16x16x32_f16(al[mi], bw[ni],
                                                             acc[mi][ni], 0, 0, 0);
      }
    __syncthreads();
  }
#pragma unroll
  for (int mi = 0; mi < 4; mi++) {
#pragma unroll
    for (int r = 0; r < 4; r++) {
      float* cp =
          C + (size_t)(bm + wm + mi * 16 + quad * 4 + r) * (HH * KK) + bn + wn + m16;
#pragma unroll
      for (int ni = 0; ni < 4; ni++) cp[ni * 16] = acc[mi][ni][r];
    }
  }
}

// ---------------------------------------------------------------------------
// alpha/beta projections (unchanged)
// ---------------------------------------------------------------------------
__global__ __launch_bounds__(64) void ab_proj(const float* __restrict__ x,
                                              const float* __restrict__ Wa,
                                              const float* __restrict__ ba,
                                              const float* __restrict__ Wb,
                                              const float* __restrict__ bb,
                                              float* __restrict__ abq) {
  const int row = blockIdx.x;
  const int g = blockIdx.y;
  const int h0 = (g & 1) * 8;
  const bool isA = (g < 2);
  const float* W = isA ? Wa : Wb;
  const int lane = threadIdx.x;
  const float* xr = x + (size_t)row * DD;
  float acc[8];
#pragma unroll
  for (int j = 0; j < 8; j++) acc[j] = 0.f;
  for (int d = lane; d < DD; d += 64) {
    const float xv = xr[d];
#pragma unroll
    for (int j = 0; j < 8; j++)
      acc[j] = fmaf(xv, W[(size_t)(h0 + j) * DD + d], acc[j]);
  }
#pragma unroll
  for (int j = 0; j < 8; j++) {
#pragma unroll
    for (int off = 32; off > 0; off >>= 1) acc[j] += __shfl_xor(acc[j], off, 64);
  }
  if (lane == 0) {
    if (isA) {
#pragma unroll
      for (int j = 0; j < 8; j++) {
        const float z = acc[j] + ba[h0 + j];
        abq[((size_t)row * HH + h0 + j) * 4 + 0] = 1.0f / (1.0f + expf(-z));
      }
    } else {
#pragma unroll
      for (int j = 0; j < 8; j++) {
        const float z = acc[j] + bb[h0 + j];
        const float sp = (z > 20.f) ? z : log1pf(expf(z));
        abq[((size_t)row * HH + h0 + j) * 4 + 1] = sp * 0.08838834764831845f;
      }
    }
  }
}

// ---------------------------------------------------------------------------
// l2-normalize q,k in place; kq = dot(qn,kn) -> abq slot 2 (unchanged)
// ---------------------------------------------------------------------------
__global__ __launch_bounds__(256) void norm_qk(float* __restrict__ q,
                                               float* __restrict__ k,
                                               float* __restrict__ abq) {
  const int vec = blockIdx.x * 4 + (threadIdx.x >> 6);
  const int l = threadIdx.x & 63;
  float* qp = q + (size_t)vec * 128;
  float* kp = k + (size_t)vec * 128;
  float q0 = qp[l], q1 = qp[l + 64];
  float k0 = kp[l], k1 = kp[l + 64];
  float sq = q0 * q0 + q1 * q1;
  float sk = k0 * k0 + k1 * k1;
#pragma unroll
  for (int off = 32; off > 0; off >>= 1) {
    sq += __shfl_xor(sq, off, 64);
    sk += __shfl_xor(sk, off, 64);
  }
  const float iq = 1.0f / fmaxf(sqrtf(sq), 1e-12f);
  const float ik = 1.0f / fmaxf(sqrtf(sk), 1e-12f);
  q0 *= iq; q1 *= iq; k0 *= ik; k1 *= ik;
  qp[l] = q0; qp[l + 64] = q1;
  kp[l] = k0; kp[l + 64] = k1;
  float pq = q0 * k0 + q1 * k1;
#pragma unroll
  for (int off = 32; off > 0; off >>= 1) pq += __shfl_xor(pq, off, 64);
  if (l == 0) abq[(size_t)vec * 4 + 2] = pq;
}

// ---------------------------------------------------------------------------
// Scan v4: 16-lane row-groups, 8 state floats/thread, all-DPP allreduce.
// NO-COPY depth-8 prefetch: step j consumes slot j, THEN reloads slot j for
// step t+8. One sched_barrier(0) after each load group pins the loads in
// their step (prevents round-3 sinking) while letting the scheduler
// interleave load issue with the FMA chain. Removes ~20 v_mov + the
// pre-compute barrier from every step.
// ---------------------------------------------------------------------------
#define DPP_ADD(x, ctrl)                                                     \
  ((x) + __int_as_float(__builtin_amdgcn_update_dpp(                         \
             0, __float_as_int(x), (ctrl), 0xF, 0xF, true)))

#define SCAN_STEP(kc0, kc1, qc0, qc1, vc, ac, store_ptr)                       \
  {                                                                            \
    float dkA = fmaf(S0, kc0.x, fmaf(S1, kc0.y, fmaf(S2, kc0.z, S3 * kc0.w))); \
    float dkB = fmaf(S4, kc1.x, fmaf(S5, kc1.y, fmaf(S6, kc1.z, S7 * kc1.w))); \
    float dqA = fmaf(S0, qc0.x, fmaf(S1, qc0.y, fmaf(S2, qc0.z, S3 * qc0.w))); \
    float dqB = fmaf(S4, qc1.x, fmaf(S5, qc1.y, fmaf(S6, qc1.z, S7 * qc1.w))); \
    float dk = dkA + dkB;                                                      \
    float dq = dqA + dqB;                                                      \
    dk = DPP_ADD(dk, 0xB1);  dq = DPP_ADD(dq, 0xB1);   /* width 2  */          \
    dk = DPP_ADD(dk, 0x4E);  dq = DPP_ADD(dq, 0x4E);   /* width 4  */          \
    dk = DPP_ADD(dk, 0x141); dq = DPP_ADD(dq, 0x141);  /* width 8  */          \
    dk = DPP_ADD(dk, 0x140); dq = DPP_ADD(dq, 0x140);  /* width 16 */          \
    const float u = ac.y * (vc - ac.x * dk);                                   \
    const float oo = fmaf(ac.x, dq, u * ac.z);                                 \
    S0 = fmaf(ac.x, S0, u * kc0.x);                                            \
    S1 = fmaf(ac.x, S1, u * kc0.y);                                            \
    S2 = fmaf(ac.x, S2, u * kc0.z);                                            \
    S3 = fmaf(ac.x, S3, u * kc0.w);                                            \
    S4 = fmaf(ac.x, S4, u * kc1.x);                                            \
    S5 = fmaf(ac.x, S5, u * kc1.y);                                            \
    S6 = fmaf(ac.x, S6, u * kc1.z);                                            \
    S7 = fmaf(ac.x, S7, u * kc1.w);                                            \
    if (g == 0) *(store_ptr) = oo;                                             \
  }

#define PD 8  // prefetch depth

__global__ __launch_bounds__(256) void scan_kernel(const float* __restrict__ q,
                                                   const float* __restrict__ k,
                                                   const float* __restrict__ v,
                                                   const float* __restrict__ abq,
                                                   float* __restrict__ o) {
  const int bid = blockIdx.x;  // = s*32 + bh
  const int bh = bid & 31;
  const int s = bid >> 5;  // 0..7
  const int h = bh & 15;
  const int b = bh >> 4;
  const int tid = threadIdx.x;
  const int w = tid >> 6;
  const int lane = tid & 63;
  const int rg = lane >> 4;  // 0..3 row within wave
  const int g = lane & 15;   // 0..15 k-group (8 floats)
  const int vrow = s * 16 + w * 4 + rg;

  const size_t base = (size_t)b * TT * 2048 + (size_t)h * KK;
  const float* kb = k + base + g * 8;
  const float* qb = q + base + g * 8;
  const float* vb = v + base + vrow;
  const float* ab = abq + ((size_t)b * TT * HH + h) * 4;
  float* ob = o + base + vrow;

  float S0 = 0.f, S1 = 0.f, S2 = 0.f, S3 = 0.f;
  float S4 = 0.f, S5 = 0.f, S6 = 0.f, S7 = 0.f;

  float4 kf0[PD], kf1[PD], qf0[PD], qf1[PD], af[PD];
  float vf[PD];
#pragma unroll
  for (int d = 0; d < PD; d++) {
    kf0[d] = *(const float4*)(kb + d * 2048);
    kf1[d] = *(const float4*)(kb + d * 2048 + 4);
    qf0[d] = *(const float4*)(qb + d * 2048);
    qf1[d] = *(const float4*)(qb + d * 2048 + 4);
    vf[d] = vb[d * 2048];
    af[d] = *(const float4*)(ab + d * 64);
  }

  int off = 0;   // uniform element offset, +2048 per step
  int aoff = 0;  // uniform abq offset, +64 per step
  for (int t0 = 0; t0 < TT - PD; t0 += PD) {
#pragma unroll
    for (int j = 0; j < PD; j++) {
      // consume slot j (no copy — loads below overwrite it afterwards)
      SCAN_STEP(kf0[j], kf1[j], qf0[j], qf1[j], vf[j], af[j],
                ob + off + j * 2048);
      // reload slot j with step t0+j+PD
      kf0[j] = *(const float4*)(kb + off + (j + PD) * 2048);
      kf1[j] = *(const float4*)(kb + off + (j + PD) * 2048 + 4);
      qf0[j] = *(const float4*)(qb + off + (j + PD) * 2048);
      qf1[j] = *(const float4*)(qb + off + (j + PD) * 2048 + 4);
      vf[j] = vb[off + (j + PD) * 2048];
      af[j] = *(const float4*)(ab + aoff + (j + PD) * 64);
      __builtin_amdgcn_sched_barrier(0);  // loads may not sink past here
    }
    off += PD * 2048;
    aoff += PD * 64;
  }
  // final PD steps: consume only
#pragma unroll
  for (int j = 0; j < PD; j++) {
    SCAN_STEP(kf0[j], kf1[j], qf0[j], qf1[j], vf[j], af[j], ob + off + j * 2048);
  }
}

// ---------------------------------------------------------------------------
extern "C" void kernel_launch(void* const* d_in, const int* in_sizes, int n_in,
                              void* d_out, int out_size, void* d_ws,
                              size_t ws_size, hipStream_t stream) {
  const float* x = (const float*)d_in[0];
  const float* Wq = (const float*)d_in[1];
  const float* Wk = (const float*)d_in[2];
  const float* Wv = (const float*)d_in[3];
  const float* Wa = (const float*)d_in[4];
  const float* ba = (const float*)d_in[5];
  const float* Wb = (const float*)d_in[6];
  const float* bb = (const float*)d_in[7];
  float* out = (float*)d_out;
  float* ws = (float*)d_ws;

  const size_t PROJ = (size_t)BB * TT * HH * KK;  // 8,388,608
  const size_t NABQ = (size_t)BB * TT * HH * 4;
  float* qw = ws;
  float* kw = ws + PROJ;
  float* vw = ws + 2 * PROJ;
  float* abq = ws + 3 * PROJ;
  _Float16* xh = (_Float16*)(abq + NABQ);
  _Float16* xl = xh + (size_t)BB * TT * DD;
  _Float16* Wf = xl + (size_t)BB * TT * DD;
  const size_t NEED = (3 * PROJ + NABQ) * 4 +
                      ((size_t)BB * TT * DD * 2 + 3 * (size_t)(HH * KK) * DD) * 2;

  const int M = BB * TT;  // 4096
  const int N = HH * KK;  // 2048
  if (ws_size >= NEED) {
    const int cgrid = (int)(((size_t)BB * TT * DD / 4 + 3 * (size_t)N * DD / 4) / 256);
    convert_f16<<<cgrid, 256, 0, stream>>>(x, Wq, Wk, Wv, xh, xl, Wf);
    gemm_mfma<<<dim3(N / 128, M / 128, 3), 256, 0, stream>>>(xh, xl, Wf, qw);
  } else {
    gemm_nt3<<<dim3(N / 128, M / 128, 3), 256, 0, stream>>>(x, Wq, Wk, Wv, qw,
                                                            M, N, DD);
  }
  ab_proj<<<dim3(M, 4), 64, 0, stream>>>(x, Wa, ba, Wb, bb, abq);
  norm_qk<<<(BB * TT * HH) / 4, 256, 0, stream>>>(qw, kw, abq);
  scan_kernel<<<BB * HH * 8, 256, 0, stream>>>(qw, kw, vw, abq, out);
}